// Round 2
// baseline (1008.246 us; speedup 1.0000x reference)
//
#include <hip/hip_runtime.h>
#include <hip/hip_bf16.h>

typedef __hip_bfloat16 bf16;
typedef __attribute__((ext_vector_type(8))) short bf16x8;
typedef __attribute__((ext_vector_type(4))) float f32x4;

#define NPTS 100000
#define KNN 16
#define NKTOT 1600000
#define NB_W 6250      // w-path blocks (256 nk each)
#define NB_F 1563      // f-path blocks (64 points each, MFMA)

// ---- stats region (float offsets within ws) ----
#define P_Y1 0
#define P_Z1 1024
#define P_Y2 9216
#define P_Z2 10240
#define P_Y3 18432
#define P_LIN 20480
#define F_Y1 28672
#define F_Z1 28688
#define F_Y2 28816
#define F_Z2 28832
#define F_Y3 28960
#define F_LIN 28992
// cnt histogram (int) at byte offset 131072, 100000 ints
#define CNT_BYTE 131072ull
#define ZERO_BYTES 531072ull   // stats + cnt

// ---- big buffers (byte offsets, 1MB-aligned) ----
#define OFS_Y1  (1ull<<20)                  // y1 bf16 [8][NKTOT]     = 25.6 MB
#define OFS_ZP1 (28ull<<20)                 // zp1 fp32 [NPTS][64]    = 25.6 MB
#define OFS_ZP2 (56ull<<20)                 // zp2 fp32 [NPTS][64]    = 25.6 MB
#define OFS_LWB (86ull<<20)                 // lin_w bf16 [64][1024]  = 128 KB
#define WS_NEED (OFS_LWB + 131072ull)       // ~90.3 MB

__device__ inline float bf2f(bf16 v) { return __bfloat162float(v); }
__device__ inline short f2bfs(float x) {
  bf16 h = __float2bfloat16(x);
  short s; __builtin_memcpy(&s, &h, 2); return s;
}

__device__ inline void wave_stat(float v, float* sums, float* sqs, int ch) {
  float s = v, q = v * v;
  #pragma unroll
  for (int o = 32; o > 0; o >>= 1) { s += __shfl_xor(s, o); q += __shfl_xor(q, o); }
  if ((threadIdx.x & 63) == 0) { atomicAdd(sums + ch, s); atomicAdd(sqs + ch, q); }
}

// ================= K1: gather + geometry + w-conv1 (+ cnt histogram, + lwb convert) =================
__global__ __launch_bounds__(256) void k1(
    const float* __restrict__ xyz, const float* __restrict__ cov,
    const float* __restrict__ feats, const int* __restrict__ knn,
    const float* __restrict__ ww1, const float* __restrict__ wb1,
    const float* __restrict__ linw,
    float* __restrict__ stats, int* __restrict__ cnt,
    bf16* __restrict__ Y1, bf16* __restrict__ lwb) {
  const int t = threadIdx.x;
  if (blockIdx.x >= NB_W) {
    // lin_w fp32 -> bf16 copy: 64 blocks x 1024 elems
    int e = (blockIdx.x - NB_W) * 1024 + t * 4;
    if (e < 65536) {
      float4 v = *(const float4*)(linw + e);
      lwb[e+0] = __float2bfloat16(v.x); lwb[e+1] = __float2bfloat16(v.y);
      lwb[e+2] = __float2bfloat16(v.z); lwb[e+3] = __float2bfloat16(v.w);
    }
    return;
  }
  __shared__ int   s_idx[256];
  __shared__ float s_xyz[256][3];
  __shared__ float s_cov[256][9];
  __shared__ float s_nrm[256][3];
  __shared__ float s_ww1t[14][8];
  const long base = (long)blockIdx.x * 256;
  s_idx[t] = knn[base + t];
  if (t < 112) { int c = t >> 3, h = t & 7; s_ww1t[c][h] = ww1[h * 14 + c]; }
  __syncthreads();
  const int idx = s_idx[t];
  atomicAdd(&cnt[idx], 1);
  s_xyz[t][0] = xyz[idx*3+0]; s_xyz[t][1] = xyz[idx*3+1]; s_xyz[t][2] = xyz[idx*3+2];
  #pragma unroll
  for (int j = 0; j < 9; j++) s_cov[t][j] = cov[(size_t)idx*9+j];
  s_nrm[t][0] = feats[(size_t)idx*64+3];
  s_nrm[t][1] = feats[(size_t)idx*64+4];
  s_nrm[t][2] = feats[(size_t)idx*64+5];
  __syncthreads();
  const int b = (t >> 4) << 4;   // neighbor-0 row of this point
  float lx = s_xyz[t][0]-s_xyz[b][0], ly = s_xyz[t][1]-s_xyz[b][1], lz = s_xyz[t][2]-s_xyz[b][2];
  float t9v = sqrtf(lx*lx + ly*ly + lz*lz);
  float rn = 1.0f / fmaxf(t9v, 1e-12f);
  float rx = lx*rn, ry = ly*rn, rz = lz*rn;
  float nmx = s_nrm[b][0], nmy = s_nrm[b][1], nmz = s_nrm[b][2];  // n_miu
  float nax = s_nrm[t][0], nay = s_nrm[t][1], naz = s_nrm[t][2];  // n_alpha
  float t2v = nmx*rx + nmy*ry + nmz*rz;
  float vx = nmx - t2v*rx, vy = nmy - t2v*ry, vz = nmz - t2v*rz;
  float vn = 1.0f / fmaxf(sqrtf(vx*vx+vy*vy+vz*vz), 1e-12f);
  vx *= vn; vy *= vn; vz *= vn;
  float wxv = ry*vz - rz*vy, wyv = rz*vx - rx*vz, wzv = rx*vy - ry*vx;
  float wn = 1.0f / fmaxf(sqrtf(wxv*wxv+wyv*wyv+wzv*wzv), 1e-12f);
  wxv *= wn; wyv *= wn; wzv *= wn;
  float t1v = nax*nmx + nay*nmy + naz*nmz;
  float t3v = rx*nax + ry*nay + rz*naz;
  float t4v = lx*nmx + ly*nmy + lz*nmz;
  float t6v = nax*vx + nay*vy + naz*vz;
  float t7v = nax*wxv + nay*wyv + naz*wzv;
  float cxx = nay*nmz - naz*nmy, cyy = naz*nmx - nax*nmz, czz = nax*nmy - nay*nmx;
  float t8v = lx*cxx + ly*cyy + lz*czz;
  const float* m1 = s_cov[t];
  float q0 = m1[0]*lx + m1[1]*ly + m1[2]*lz;
  float q1 = m1[3]*lx + m1[4]*ly + m1[5]*lz;
  float q2 = m1[6]*lx + m1[7]*ly + m1[8]*lz;
  float s1v = lx*q0 + ly*q1 + lz*q2;
  const float* m0 = s_cov[b];
  float p0 = m0[0]*lx + m0[1]*ly + m0[2]*lz;
  float p1 = m0[3]*lx + m0[4]*ly + m0[5]*lz;
  float p2 = m0[6]*lx + m0[7]*ly + m0[8]*lz;
  float s2v = lx*p0 + ly*p1 + lz*p2;
  float win[14] = {lx, ly, lz, t1v, t2v, t3v, t4v, t3v, t6v, t7v, t8v, t9v, s1v, s2v};
  const long nkg = base + t;
  const int slot = blockIdx.x & 63;
  float y[8];
  #pragma unroll
  for (int h = 0; h < 8; h++) y[h] = wb1[h];
  #pragma unroll
  for (int c = 0; c < 14; c++) {
    float x = win[c];
    #pragma unroll
    for (int h = 0; h < 8; h++) y[h] = fmaf(s_ww1t[c][h], x, y[h]);
  }
  float* su = stats + P_Y1 + slot * 16;
  #pragma unroll
  for (int h = 0; h < 8; h++) {
    Y1[(size_t)h * NKTOT + nkg] = __float2bfloat16(y[h]);
    wave_stat(y[h], su, su + 8, h);
  }
}

// ================= kfin: finalize up to two BN layers =================
__global__ __launch_bounds__(64) void kfin(
    float* __restrict__ stats,
    int pA, int cA, int fA, const float* gA, const float* beA, float mA,
    int pB, int cB, int fB, const float* gB, const float* beB, float mB) {
  int p, C, f; const float *g, *be; float M;
  if (blockIdx.x == 0) { p=pA; C=cA; f=fA; g=gA; be=beA; M=mA; }
  else                 { p=pB; C=cB; f=fB; g=gB; be=beB; M=mB; }
  int c = threadIdx.x;
  if (c >= C) return;
  float s = 0.f, q = 0.f;
  for (int sl = 0; sl < 64; sl++) { s += stats[p + sl*2*C + c]; q += stats[p + sl*2*C + C + c]; }
  float mean = s / M;
  float var = q / M - mean * mean;
  float scale = g[c] / sqrtf(var + 1e-5f);
  stats[f + c] = scale;
  stats[f + C + c] = be[c] - mean * scale;
}

// ================= f-path per-point MFMA conv helper (used by K2/K3 f-blocks) =================
// Computes zp_out[p][h] = bias[h] + sum_c A[p][c] * W[h][c] for 64 points, A staged in LDS bf16.
// Weighted stats (weight = cnt[p]) accumulated to stats+pofs.

// ================= K2: w-path y2 stats + f-path conv1 (zp1) =================
__global__ __launch_bounds__(256) void k2(
    const bf16* __restrict__ Y1, const float* __restrict__ ww2, const float* __restrict__ wb2,
    const float* __restrict__ feats, const float* __restrict__ fw1, const float* __restrict__ fb1,
    const int* __restrict__ cnt,
    float* __restrict__ stats, float* __restrict__ zp1) {
  const int t = threadIdx.x;
  if (blockIdx.x < NB_W) {
    // ---- w-path: stats(y2) ----
    __shared__ float s_ww2t[8][8];
    __shared__ float s_sc[8], s_sh[8];
    if (t < 64) { int c = t >> 3, h = t & 7; s_ww2t[c][h] = ww2[h*8+c]; }
    if (t < 8)  { s_sc[t] = stats[F_Y1 + t]; s_sh[t] = stats[F_Y1 + 8 + t]; }
    __syncthreads();
    const long nkg = (long)blockIdx.x * 256 + t;
    float a[8];
    #pragma unroll
    for (int c = 0; c < 8; c++)
      a[c] = fmaxf(fmaf(s_sc[c], bf2f(Y1[(size_t)c * NKTOT + nkg]), s_sh[c]), 0.f);
    float y2[8];
    #pragma unroll
    for (int h = 0; h < 8; h++) y2[h] = wb2[h];
    #pragma unroll
    for (int c = 0; c < 8; c++)
      #pragma unroll
      for (int h = 0; h < 8; h++) y2[h] = fmaf(s_ww2t[c][h], a[c], y2[h]);
    const int slot = blockIdx.x & 63;
    float* su = stats + P_Y2 + slot * 16;
    #pragma unroll
    for (int h = 0; h < 8; h++) wave_stat(y2[h], su, su + 8, h);
    return;
  }
  // ---- f-path: zp1 = feats @ fw1^T + fb1 (MFMA), weighted stats(z1) ----
  __shared__ __align__(16) bf16 s_A[64 * 72];
  __shared__ float s_sum[64], s_sq[64];
  const int fblk = blockIdx.x - NB_W;
  const int p0 = fblk * 64;
  if (t < 64) { s_sum[t] = 0.f; s_sq[t] = 0.f; }
  for (int r = 0; r < 16; r++) {
    int e = r * 256 + t;
    int p = e >> 6, c = e & 63;
    int gp = p0 + p;
    float v = (gp < NPTS) ? feats[(size_t)gp*64 + c] : 0.f;
    s_A[p * 72 + c] = __float2bfloat16(v);
  }
  __syncthreads();
  const int wv = t >> 6, lane = t & 63, pt = lane & 15, kq = lane >> 4;
  for (int nt = 0; nt < 4; nt++) {
    f32x4 acc = {0.f, 0.f, 0.f, 0.f};
    int h = nt * 16 + pt;
    #pragma unroll
    for (int ks = 0; ks < 2; ks++) {
      bf16x8 av = *(const bf16x8*)&s_A[(wv*16 + pt) * 72 + ks*32 + kq*8];
      float4 b0 = *(const float4*)(fw1 + h*64 + ks*32 + kq*8);
      float4 b1 = *(const float4*)(fw1 + h*64 + ks*32 + kq*8 + 4);
      bf16x8 bv;
      bv[0]=f2bfs(b0.x); bv[1]=f2bfs(b0.y); bv[2]=f2bfs(b0.z); bv[3]=f2bfs(b0.w);
      bv[4]=f2bfs(b1.x); bv[5]=f2bfs(b1.y); bv[6]=f2bfs(b1.z); bv[7]=f2bfs(b1.w);
      acc = __builtin_amdgcn_mfma_f32_16x16x32_bf16(av, bv, acc, 0, 0, 0);
    }
    float bias = fb1[h];
    float ss = 0.f, qq = 0.f;
    #pragma unroll
    for (int r = 0; r < 4; r++) {
      int gp = p0 + wv*16 + kq*4 + r;
      float z = acc[r] + bias;
      if (gp < NPTS) {
        zp1[(size_t)gp*64 + h] = z;
        float w = (float)cnt[gp];
        ss += w * z; qq += w * z * z;
      }
    }
    ss += __shfl_xor(ss, 16); ss += __shfl_xor(ss, 32);
    qq += __shfl_xor(qq, 16); qq += __shfl_xor(qq, 32);
    if (lane < 16) { atomicAdd(&s_sum[h], ss); atomicAdd(&s_sq[h], qq); }
  }
  __syncthreads();
  if (t < 64) {
    int slot = blockIdx.x & 63;
    atomicAdd(stats + P_Z1 + slot*128 + t, s_sum[t]);
    atomicAdd(stats + P_Z1 + slot*128 + 64 + t, s_sq[t]);
  }
}

// ================= K3: w-path y3 stats + f-path conv2 (zp2) =================
__global__ __launch_bounds__(256) void k3(
    const bf16* __restrict__ Y1,
    const float* __restrict__ ww2, const float* __restrict__ wb2,
    const float* __restrict__ ww3, const float* __restrict__ wb3,
    const float* __restrict__ zp1, const float* __restrict__ fw2, const float* __restrict__ fb2,
    const int* __restrict__ cnt,
    float* __restrict__ stats, float* __restrict__ zp2) {
  const int t = threadIdx.x;
  if (blockIdx.x < NB_W) {
    __shared__ float s_ww2t[8][8];
    __shared__ float s_ww3t[8][16];
    __shared__ float s_sc1[8], s_sh1[8], s_sc2[8], s_sh2[8];
    if (t < 64)  { int c = t >> 3, h = t & 7; s_ww2t[c][h] = ww2[h*8+c]; }
    if (t < 128) { int h = t >> 4, m = t & 15; s_ww3t[h][m] = ww3[m*8+h]; }
    if (t < 8)  { s_sc1[t] = stats[F_Y1 + t]; s_sh1[t] = stats[F_Y1 + 8 + t]; }
    if (t >= 8 && t < 16) { s_sc2[t-8] = stats[F_Y2 + (t-8)]; s_sh2[t-8] = stats[F_Y2 + 8 + (t-8)]; }
    __syncthreads();
    const long nkg = (long)blockIdx.x * 256 + t;
    float a[8];
    #pragma unroll
    for (int c = 0; c < 8; c++)
      a[c] = fmaxf(fmaf(s_sc1[c], bf2f(Y1[(size_t)c * NKTOT + nkg]), s_sh1[c]), 0.f);
    float y2[8];
    #pragma unroll
    for (int h = 0; h < 8; h++) y2[h] = wb2[h];
    #pragma unroll
    for (int c = 0; c < 8; c++)
      #pragma unroll
      for (int h = 0; h < 8; h++) y2[h] = fmaf(s_ww2t[c][h], a[c], y2[h]);
    float a2[8];
    #pragma unroll
    for (int h = 0; h < 8; h++) a2[h] = fmaxf(fmaf(s_sc2[h], y2[h], s_sh2[h]), 0.f);
    float y3[16];
    #pragma unroll
    for (int m = 0; m < 16; m++) y3[m] = wb3[m];
    #pragma unroll
    for (int h = 0; h < 8; h++)
      #pragma unroll
      for (int m = 0; m < 16; m++) y3[m] = fmaf(s_ww3t[h][m], a2[h], y3[m]);
    const int slot = blockIdx.x & 63;
    float* su = stats + P_Y3 + slot * 32;
    #pragma unroll
    for (int m = 0; m < 16; m++) wave_stat(y3[m], su, su + 16, m);
    return;
  }
  // ---- f-path: zp2 = relu(bn(zp1)) @ fw2^T + fb2 (MFMA), weighted stats(z2) ----
  __shared__ __align__(16) bf16 s_A[64 * 72];
  __shared__ float s_sum[64], s_sq[64];
  __shared__ float s_sc[64], s_sh[64];
  const int fblk = blockIdx.x - NB_W;
  const int p0 = fblk * 64;
  if (t < 64) { s_sum[t] = 0.f; s_sq[t] = 0.f; s_sc[t] = stats[F_Z1 + t]; s_sh[t] = stats[F_Z1 + 64 + t]; }
  __syncthreads();
  for (int r = 0; r < 16; r++) {
    int e = r * 256 + t;
    int p = e >> 6, c = e & 63;
    int gp = p0 + p;
    float v = 0.f;
    if (gp < NPTS) v = fmaxf(fmaf(s_sc[c], zp1[(size_t)gp*64 + c], s_sh[c]), 0.f);
    s_A[p * 72 + c] = __float2bfloat16(v);
  }
  __syncthreads();
  const int wv = t >> 6, lane = t & 63, pt = lane & 15, kq = lane >> 4;
  for (int nt = 0; nt < 4; nt++) {
    f32x4 acc = {0.f, 0.f, 0.f, 0.f};
    int h = nt * 16 + pt;
    #pragma unroll
    for (int ks = 0; ks < 2; ks++) {
      bf16x8 av = *(const bf16x8*)&s_A[(wv*16 + pt) * 72 + ks*32 + kq*8];
      float4 b0 = *(const float4*)(fw2 + h*64 + ks*32 + kq*8);
      float4 b1 = *(const float4*)(fw2 + h*64 + ks*32 + kq*8 + 4);
      bf16x8 bv;
      bv[0]=f2bfs(b0.x); bv[1]=f2bfs(b0.y); bv[2]=f2bfs(b0.z); bv[3]=f2bfs(b0.w);
      bv[4]=f2bfs(b1.x); bv[5]=f2bfs(b1.y); bv[6]=f2bfs(b1.z); bv[7]=f2bfs(b1.w);
      acc = __builtin_amdgcn_mfma_f32_16x16x32_bf16(av, bv, acc, 0, 0, 0);
    }
    float bias = fb2[h];
    float ss = 0.f, qq = 0.f;
    #pragma unroll
    for (int r = 0; r < 4; r++) {
      int gp = p0 + wv*16 + kq*4 + r;
      float z = acc[r] + bias;
      if (gp < NPTS) {
        zp2[(size_t)gp*64 + h] = z;
        float w = (float)cnt[gp];
        ss += w * z; qq += w * z * z;
      }
    }
    ss += __shfl_xor(ss, 16); ss += __shfl_xor(ss, 32);
    qq += __shfl_xor(qq, 16); qq += __shfl_xor(qq, 32);
    if (lane < 16) { atomicAdd(&s_sum[h], ss); atomicAdd(&s_sq[h], qq); }
  }
  __syncthreads();
  if (t < 64) {
    int slot = blockIdx.x & 63;
    atomicAdd(stats + P_Z2 + slot*128 + t, s_sum[t]);
    atomicAdd(stats + P_Z2 + slot*128 + 64 + t, s_sq[t]);
  }
}

// ================= K4: fused w-recompute + a2 gather + new + linear (MFMA) + lin stats =================
__global__ __launch_bounds__(256) void k4(
    const bf16* __restrict__ Y1, const int* __restrict__ knn,
    const float* __restrict__ ww2, const float* __restrict__ wb2,
    const float* __restrict__ ww3, const float* __restrict__ wb3,
    const float* __restrict__ zp2, const bf16* __restrict__ lwb, const float* __restrict__ linb,
    float* __restrict__ stats, float* __restrict__ outp) {
  __shared__ int s_idx[256];
  __shared__ float s_ww2t[8][8];
  __shared__ float s_ww3t[8][16];
  __shared__ float s_scy1[8], s_shy1[8], s_scy2[8], s_shy2[8];
  __shared__ float s_scy3[16], s_shy3[16];
  __shared__ float s_scf[64], s_shf[64];
  __shared__ __align__(16) bf16 s_w[16 * 392];     // [p][k][m]: p*392 + k*24 + m
  __shared__ __align__(16) bf16 s_new[16 * 1032];  // [p][i-swizzled], row stride 1032
  const int t = threadIdx.x;
  const long base = (long)blockIdx.x * 256;
  s_idx[t] = knn[base + t];
  if (t < 64)  { int c = t >> 3, h = t & 7; s_ww2t[c][h] = ww2[h*8+c]; }
  if (t < 128) { int h = t >> 4, m = t & 15; s_ww3t[h][m] = ww3[m*8+h]; }
  if (t < 8)  { s_scy1[t] = stats[F_Y1 + t]; s_shy1[t] = stats[F_Y1 + 8 + t]; }
  if (t >= 8 && t < 16) { s_scy2[t-8] = stats[F_Y2 + (t-8)]; s_shy2[t-8] = stats[F_Y2 + 8 + (t-8)]; }
  if (t >= 16 && t < 32) { s_scy3[t-16] = stats[F_Y3 + (t-16)]; s_shy3[t-16] = stats[F_Y3 + 16 + (t-16)]; }
  if (t >= 32 && t < 96) { s_scf[t-32] = stats[F_Z2 + (t-32)]; s_shf[t-32] = stats[F_Z2 + 64 + (t-32)]; }
  __syncthreads();

  // ---- phase 1: recompute w-path for this thread's nk ----
  {
    const long nkg = base + t;
    float a[8];
    #pragma unroll
    for (int c = 0; c < 8; c++)
      a[c] = fmaxf(fmaf(s_scy1[c], bf2f(Y1[(size_t)c * NKTOT + nkg]), s_shy1[c]), 0.f);
    float y2[8];
    #pragma unroll
    for (int h = 0; h < 8; h++) y2[h] = wb2[h];
    #pragma unroll
    for (int c = 0; c < 8; c++)
      #pragma unroll
      for (int h = 0; h < 8; h++) y2[h] = fmaf(s_ww2t[c][h], a[c], y2[h]);
    float a2[8];
    #pragma unroll
    for (int h = 0; h < 8; h++) a2[h] = fmaxf(fmaf(s_scy2[h], y2[h], s_shy2[h]), 0.f);
    float y3[16];
    #pragma unroll
    for (int m = 0; m < 16; m++) y3[m] = wb3[m];
    #pragma unroll
    for (int h = 0; h < 8; h++)
      #pragma unroll
      for (int m = 0; m < 16; m++) y3[m] = fmaf(s_ww3t[h][m], a2[h], y3[m]);
    const int p = t >> 4, k = t & 15;
    #pragma unroll
    for (int mp = 0; mp < 8; mp++) {
      float w0 = fmaxf(fmaf(s_scy3[2*mp],   y3[2*mp],   s_shy3[2*mp]),   0.f);
      float w1 = fmaxf(fmaf(s_scy3[2*mp+1], y3[2*mp+1], s_shy3[2*mp+1]), 0.f);
      __hip_bfloat162 pk; pk.x = __float2bfloat16(w0); pk.y = __float2bfloat16(w1);
      *(__hip_bfloat162*)&s_w[p*392 + k*24 + 2*mp] = pk;
    }
  }
  __syncthreads();

  // ---- phase 2: new[p][h*16+m] = sum_k f[h][k]*w[m][k], f gathered from zp2 ----
  {
    const int p = t >> 4, l = t & 15;
    float sc0 = s_scf[l*4+0], sc1 = s_scf[l*4+1], sc2 = s_scf[l*4+2], sc3 = s_scf[l*4+3];
    float sh0 = s_shf[l*4+0], sh1 = s_shf[l*4+1], sh2 = s_shf[l*4+2], sh3 = s_shf[l*4+3];
    float acc[4][16];
    #pragma unroll
    for (int hj = 0; hj < 4; hj++)
      #pragma unroll
      for (int m = 0; m < 16; m++) acc[hj][m] = 0.f;
    #pragma unroll 4
    for (int k = 0; k < 16; k++) {
      int idx = s_idx[(p << 4) + k];
      float4 zf = *(const float4*)(zp2 + (size_t)idx*64 + (l << 2));
      float f0 = fmaxf(fmaf(sc0, zf.x, sh0), 0.f);
      float f1 = fmaxf(fmaf(sc1, zf.y, sh1), 0.f);
      float f2 = fmaxf(fmaf(sc2, zf.z, sh2), 0.f);
      float f3 = fmaxf(fmaf(sc3, zf.w, sh3), 0.f);
      #pragma unroll
      for (int mp = 0; mp < 8; mp++) {
        __hip_bfloat162 wp = *(const __hip_bfloat162*)&s_w[p*392 + k*24 + 2*mp];
        float w0 = __bfloat162float(wp.x), w1 = __bfloat162float(wp.y);
        acc[0][2*mp]   = fmaf(f0, w0, acc[0][2*mp]);   acc[0][2*mp+1] = fmaf(f0, w1, acc[0][2*mp+1]);
        acc[1][2*mp]   = fmaf(f1, w0, acc[1][2*mp]);   acc[1][2*mp+1] = fmaf(f1, w1, acc[1][2*mp+1]);
        acc[2][2*mp]   = fmaf(f2, w0, acc[2][2*mp]);   acc[2][2*mp+1] = fmaf(f2, w1, acc[2][2*mp+1]);
        acc[3][2*mp]   = fmaf(f3, w0, acc[3][2*mp]);   acc[3][2*mp+1] = fmaf(f3, w1, acc[3][2*mp+1]);
      }
    }
    // write s_new with XOR swizzle (bits 3..5 ^ (l&7))
    const int swz = (l & 7) * 8;
    #pragma unroll
    for (int hj = 0; hj < 4; hj++)
      #pragma unroll
      for (int mp = 0; mp < 8; mp++) {
        int v = hj*16 + 2*mp;
        int phys = (l << 6) + (v ^ swz);
        __hip_bfloat162 pk;
        pk.x = __float2bfloat16(acc[hj][2*mp]); pk.y = __float2bfloat16(acc[hj][2*mp+1]);
        *(__hip_bfloat162*)&s_new[p*1032 + phys] = pk;
      }
  }
  __syncthreads();

  // ---- phase 3: out = new(16x1024) @ lwb^T(1024x64) + linb via MFMA ----
  {
    const int wv = t >> 6, lane = t & 63, pt = lane & 15, kq = lane >> 4;
    const int j = wv * 16 + pt;
    const bf16* lwrow = lwb + j * 1024;
    f32x4 acc = {0.f, 0.f, 0.f, 0.f};
    #pragma unroll 8
    for (int ks = 0; ks < 32; ks++) {
      int i = ks*32 + kq*8;
      int l2 = i >> 6, v = i & 63;
      int phys = (l2 << 6) + (v ^ ((l2 & 7) * 8));
      bf16x8 av = *(const bf16x8*)&s_new[pt*1032 + phys];
      bf16x8 bv = *(const bf16x8*)(lwrow + i);
      acc = __builtin_amdgcn_mfma_f32_16x16x32_bf16(av, bv, acc, 0, 0, 0);
    }
    float bj = linb[j];
    float ss = 0.f, qq = 0.f;
    #pragma unroll
    for (int r = 0; r < 4; r++) {
      int gp = (int)(blockIdx.x * 16) + kq*4 + r;
      float val = acc[r] + bj;
      outp[(size_t)gp*64 + j] = val;
      ss += val; qq += val * val;
    }
    ss += __shfl_xor(ss, 16); ss += __shfl_xor(ss, 32);
    qq += __shfl_xor(qq, 16); qq += __shfl_xor(qq, 32);
    if (lane < 16) {
      int slot = blockIdx.x & 63;
      atomicAdd(stats + P_LIN + slot*128 + j, ss);
      atomicAdd(stats + P_LIN + slot*128 + 64 + j, qq);
    }
  }
}

// ================= K6: final BN + ReLU in-place on d_out =================
__global__ __launch_bounds__(256) void k6(float* __restrict__ outp, const float* __restrict__ stats) {
  long e = (long)blockIdx.x * 256 + threadIdx.x;
  int j = (int)(e & 63);
  float sc = stats[F_LIN + j], sh = stats[F_LIN + 64 + j];
  float v = outp[e];
  outp[e] = fmaxf(fmaf(sc, v, sh), 0.f);
}

// signature if workspace too small: absmax ~= ws_size in MB
__global__ void k_wsfail(float* outp, float mb) {
  outp[threadIdx.x] = -mb;
}

extern "C" void kernel_launch(void* const* d_in, const int* in_sizes, int n_in,
                              void* d_out, int out_size, void* d_ws, size_t ws_size,
                              hipStream_t stream) {
  const float* xyz  = (const float*)d_in[0];
  const float* cov  = (const float*)d_in[1];
  const float* feats= (const float*)d_in[2];
  const int*   knn  = (const int*)d_in[3];
  const float* fw1  = (const float*)d_in[4];
  const float* fb1  = (const float*)d_in[5];
  const float* fg1  = (const float*)d_in[6];
  const float* fbe1 = (const float*)d_in[7];
  const float* fw2  = (const float*)d_in[8];
  const float* fb2  = (const float*)d_in[9];
  const float* fg2  = (const float*)d_in[10];
  const float* fbe2 = (const float*)d_in[11];
  const float* ww1  = (const float*)d_in[12];
  const float* wb1  = (const float*)d_in[13];
  const float* wg1  = (const float*)d_in[14];
  const float* wbe1 = (const float*)d_in[15];
  const float* ww2  = (const float*)d_in[16];
  const float* wb2  = (const float*)d_in[17];
  const float* wg2  = (const float*)d_in[18];
  const float* wbe2 = (const float*)d_in[19];
  const float* ww3  = (const float*)d_in[20];
  const float* wb3  = (const float*)d_in[21];
  const float* wg3  = (const float*)d_in[22];
  const float* wbe3 = (const float*)d_in[23];
  const float* linw = (const float*)d_in[24];
  const float* linb = (const float*)d_in[25];
  const float* bng  = (const float*)d_in[26];
  const float* bnb  = (const float*)d_in[27];

  float* outp = (float*)d_out;
  if (ws_size < WS_NEED) {
    hipLaunchKernelGGL(k_wsfail, dim3(1), dim3(256), 0, stream, outp, (float)(ws_size >> 20));
    return;
  }
  char* ws = (char*)d_ws;
  float* stats = (float*)ws;
  int*   cnt   = (int*)(ws + CNT_BYTE);
  bf16*  Y1    = (bf16*)(ws + OFS_Y1);
  float* zp1   = (float*)(ws + OFS_ZP1);
  float* zp2   = (float*)(ws + OFS_ZP2);
  bf16*  lwb   = (bf16*)(ws + OFS_LWB);

  hipMemsetAsync(d_ws, 0, ZERO_BYTES, stream);
  hipLaunchKernelGGL(k1, dim3(NB_W + 64), dim3(256), 0, stream,
                     xyz, cov, feats, knn, ww1, wb1, linw, stats, cnt, Y1, lwb);
  hipLaunchKernelGGL(kfin, dim3(1), dim3(64), 0, stream, stats,
                     P_Y1, 8, F_Y1, wg1, wbe1, (float)NKTOT,
                     P_Y1, 8, F_Y1, wg1, wbe1, (float)NKTOT);
  hipLaunchKernelGGL(k2, dim3(NB_W + NB_F), dim3(256), 0, stream,
                     Y1, ww2, wb2, feats, fw1, fb1, cnt, stats, zp1);
  hipLaunchKernelGGL(kfin, dim3(2), dim3(64), 0, stream, stats,
                     P_Y2, 8, F_Y2, wg2, wbe2, (float)NKTOT,
                     P_Z1, 64, F_Z1, fg1, fbe1, (float)NKTOT);
  hipLaunchKernelGGL(k3, dim3(NB_W + NB_F), dim3(256), 0, stream,
                     Y1, ww2, wb2, ww3, wb3, zp1, fw2, fb2, cnt, stats, zp2);
  hipLaunchKernelGGL(kfin, dim3(2), dim3(64), 0, stream, stats,
                     P_Y3, 16, F_Y3, wg3, wbe3, (float)NKTOT,
                     P_Z2, 64, F_Z2, fg2, fbe2, (float)NKTOT);
  hipLaunchKernelGGL(k4, dim3(NB_W), dim3(256), 0, stream,
                     Y1, knn, ww2, wb2, ww3, wb3, zp2, lwb, linb, stats, outp);
  hipLaunchKernelGGL(kfin, dim3(1), dim3(64), 0, stream, stats,
                     P_LIN, 64, F_LIN, bng, bnb, (float)NPTS,
                     P_LIN, 64, F_LIN, bng, bnb, (float)NPTS);
  hipLaunchKernelGGL(k6, dim3(25000), dim3(256), 0, stream, outp, stats);
}

// Round 3
// 998.479 us; speedup vs baseline: 1.0098x; 1.0098x over previous
//
#include <hip/hip_runtime.h>
#include <hip/hip_bf16.h>

typedef __hip_bfloat16 bf16;
typedef __attribute__((ext_vector_type(8))) short bf16x8;
typedef __attribute__((ext_vector_type(4))) short bf16x4;
typedef __attribute__((ext_vector_type(4))) float f32x4;

#define NPTS 100000
#define KNN 16
#define NKTOT 1600000
#define NB_W 6250      // w-path blocks (256 nk each)
#define NB_F 1563      // f-path blocks (64 points each, MFMA)
#define NB_P 391       // P-pack blocks (256 points each)

// ---- stats region (float offsets within ws) ----
#define P_Y1 0
#define P_Z1 1024
#define P_Y2 9216
#define P_Z2 10240
#define P_Y3 18432
#define P_LIN 20480
#define F_Y1 28672
#define F_Z1 28688
#define F_Y2 28816
#define F_Z2 28832
#define F_Y3 28960
#define F_LIN 28992
#define CNT_BYTE 131072ull
#define ZERO_BYTES 531072ull   // stats + cnt

// ---- big buffers (byte offsets, MiB-aligned) ----
#define OFS_Y1  (1ull<<20)                  // Y1 bf16 [NKTOT][8]      = 25.6 MB
#define OFS_ZP1 (28ull<<20)                 // zp1 fp32 [NPTS][64]     = 25.6 MB ; reused as a2 bf16 [NPTS][64] (12.8 MB)
#define OFS_ZP2 (56ull<<20)                 // zp2 fp32 [NPTS][64]     = 25.6 MB
#define OFS_P   (82ull<<20)                 // P fp32 [NPTS][16]       = 6.4 MB
#define OFS_LWB (89ull<<20)                 // lin_w bf16 [64][1024]   = 128 KB
#define WS_NEED (OFS_LWB + 131072ull)       // ~89.1 MiB (< the 90.3 that fit)

__device__ inline float bf2f(bf16 v) { return __bfloat162float(v); }
__device__ inline float bfs2f(short s) {
  unsigned int u = ((unsigned int)(unsigned short)s) << 16;
  float f; __builtin_memcpy(&f, &u, 4); return f;
}
__device__ inline short f2bfs(float x) {
  bf16 h = __float2bfloat16(x);
  short s; __builtin_memcpy(&s, &h, 2); return s;
}

__device__ inline void wave_stat(float v, float* sums, float* sqs, int ch) {
  float s = v, q = v * v;
  #pragma unroll
  for (int o = 32; o > 0; o >>= 1) { s += __shfl_xor(s, o); q += __shfl_xor(q, o); }
  if ((threadIdx.x & 63) == 0) { atomicAdd(sums + ch, s); atomicAdd(sqs + ch, q); }
}

// ================= K0: pack geometry P[n]={xyz3,pad,nrm3,cov9} + lin_w->bf16 =================
__global__ __launch_bounds__(256) void k0(
    const float* __restrict__ xyz, const float* __restrict__ cov,
    const float* __restrict__ feats, const float* __restrict__ linw,
    float* __restrict__ P, bf16* __restrict__ lwb) {
  const int t = threadIdx.x;
  if (blockIdx.x >= NB_P) {
    int e = (blockIdx.x - NB_P) * 1024 + t * 4;
    if (e < 65536) {
      float4 v = *(const float4*)(linw + e);
      lwb[e+0] = __float2bfloat16(v.x); lwb[e+1] = __float2bfloat16(v.y);
      lwb[e+2] = __float2bfloat16(v.z); lwb[e+3] = __float2bfloat16(v.w);
    }
    return;
  }
  int n = blockIdx.x * 256 + t;
  if (n >= NPTS) return;
  float4 o0, o1, o2, o3;
  o0.x = xyz[n*3+0]; o0.y = xyz[n*3+1]; o0.z = xyz[n*3+2]; o0.w = 0.f;
  o1.x = feats[(size_t)n*64+3]; o1.y = feats[(size_t)n*64+4]; o1.z = feats[(size_t)n*64+5];
  const float* cv = cov + (size_t)n*9;
  o1.w = cv[0];
  o2.x = cv[1]; o2.y = cv[2]; o2.z = cv[3]; o2.w = cv[4];
  o3.x = cv[5]; o3.y = cv[6]; o3.z = cv[7]; o3.w = cv[8];
  float* pr = P + (size_t)n*16;
  *(float4*)(pr+0) = o0; *(float4*)(pr+4) = o1;
  *(float4*)(pr+8) = o2; *(float4*)(pr+12) = o3;
}

// ================= K1: packed gather + geometry + w-conv1 + cnt histogram =================
__global__ __launch_bounds__(256) void k1(
    const float* __restrict__ P, const int* __restrict__ knn,
    const float* __restrict__ ww1, const float* __restrict__ wb1,
    float* __restrict__ stats, int* __restrict__ cnt, bf16* __restrict__ Y1) {
  __shared__ float s_P[256][16];
  __shared__ float s_ww1t[14][8];
  const int t = threadIdx.x;
  const long base = (long)blockIdx.x * 256;
  if (t < 112) { int c = t >> 3, h = t & 7; s_ww1t[c][h] = ww1[h * 14 + c]; }
  const int idx = knn[base + t];
  atomicAdd(&cnt[idx], 1);
  const float* pr = P + (size_t)idx * 16;
  float4 r0 = *(const float4*)(pr+0);
  float4 r1 = *(const float4*)(pr+4);
  float4 r2 = *(const float4*)(pr+8);
  float4 r3 = *(const float4*)(pr+12);
  *(float4*)&s_P[t][0] = r0; *(float4*)&s_P[t][4] = r1;
  *(float4*)&s_P[t][8] = r2; *(float4*)&s_P[t][12] = r3;
  __syncthreads();
  const int b = t & ~15;   // neighbor-0 row of this thread's point
  float lx = r0.x - s_P[b][0], ly = r0.y - s_P[b][1], lz = r0.z - s_P[b][2];
  float nmx = s_P[b][4], nmy = s_P[b][5], nmz = s_P[b][6];   // n_miu
  float nax = r1.x, nay = r1.y, naz = r1.z;                  // n_alpha (own)
  float t9v = sqrtf(lx*lx + ly*ly + lz*lz);
  float rn = 1.0f / fmaxf(t9v, 1e-12f);
  float rx = lx*rn, ry = ly*rn, rz = lz*rn;
  float t2v = nmx*rx + nmy*ry + nmz*rz;
  float vx = nmx - t2v*rx, vy = nmy - t2v*ry, vz = nmz - t2v*rz;
  float vn = 1.0f / fmaxf(sqrtf(vx*vx+vy*vy+vz*vz), 1e-12f);
  vx *= vn; vy *= vn; vz *= vn;
  float wxv = ry*vz - rz*vy, wyv = rz*vx - rx*vz, wzv = rx*vy - ry*vx;
  float wn = 1.0f / fmaxf(sqrtf(wxv*wxv+wyv*wyv+wzv*wzv), 1e-12f);
  wxv *= wn; wyv *= wn; wzv *= wn;
  float t1v = nax*nmx + nay*nmy + naz*nmz;
  float t3v = rx*nax + ry*nay + rz*naz;
  float t4v = lx*nmx + ly*nmy + lz*nmz;
  float t6v = nax*vx + nay*vy + naz*vz;
  float t7v = nax*wxv + nay*wyv + naz*wzv;
  float cxx = nay*nmz - naz*nmy, cyy = naz*nmx - nax*nmz, czz = nax*nmy - nay*nmx;
  float t8v = lx*cxx + ly*cyy + lz*czz;
  // own cov: r1.w, r2.*, r3.*
  float q0 = r1.w*lx + r2.x*ly + r2.y*lz;
  float q1 = r2.z*lx + r2.w*ly + r3.x*lz;
  float q2 = r3.y*lx + r3.z*ly + r3.w*lz;
  float s1v = lx*q0 + ly*q1 + lz*q2;
  // neighbor-0 cov from LDS
  float p0 = s_P[b][7]*lx  + s_P[b][8]*ly  + s_P[b][9]*lz;
  float p1 = s_P[b][10]*lx + s_P[b][11]*ly + s_P[b][12]*lz;
  float p2 = s_P[b][13]*lx + s_P[b][14]*ly + s_P[b][15]*lz;
  float s2v = lx*p0 + ly*p1 + lz*p2;
  float win[14] = {lx, ly, lz, t1v, t2v, t3v, t4v, t3v, t6v, t7v, t8v, t9v, s1v, s2v};
  float y[8];
  #pragma unroll
  for (int h = 0; h < 8; h++) y[h] = wb1[h];
  #pragma unroll
  for (int c = 0; c < 14; c++) {
    float x = win[c];
    #pragma unroll
    for (int h = 0; h < 8; h++) y[h] = fmaf(s_ww1t[c][h], x, y[h]);
  }
  const long nkg = base + t;
  bf16x8 pk;
  #pragma unroll
  for (int h = 0; h < 8; h++) pk[h] = f2bfs(y[h]);
  *(bf16x8*)&Y1[nkg * 8] = pk;
  const int slot = blockIdx.x & 63;
  float* su = stats + P_Y1 + slot * 16;
  #pragma unroll
  for (int h = 0; h < 8; h++) wave_stat(y[h], su, su + 8, h);
}

// ================= kfin: finalize up to two BN layers =================
__global__ __launch_bounds__(64) void kfin(
    float* __restrict__ stats,
    int pA, int cA, int fA, const float* gA, const float* beA, float mA,
    int pB, int cB, int fB, const float* gB, const float* beB, float mB) {
  int p, C, f; const float *g, *be; float M;
  if (blockIdx.x == 0) { p=pA; C=cA; f=fA; g=gA; be=beA; M=mA; }
  else                 { p=pB; C=cB; f=fB; g=gB; be=beB; M=mB; }
  int c = threadIdx.x;
  if (c >= C) return;
  float s = 0.f, q = 0.f;
  for (int sl = 0; sl < 64; sl++) { s += stats[p + sl*2*C + c]; q += stats[p + sl*2*C + C + c]; }
  float mean = s / M;
  float var = q / M - mean * mean;
  float scale = g[c] / sqrtf(var + 1e-5f);
  stats[f + c] = scale;
  stats[f + C + c] = be[c] - mean * scale;
}

// ================= K2: w-path y2 stats + f-path conv1 (zp1) =================
__global__ __launch_bounds__(256) void k2(
    const bf16* __restrict__ Y1, const float* __restrict__ ww2, const float* __restrict__ wb2,
    const float* __restrict__ feats, const float* __restrict__ fw1, const float* __restrict__ fb1,
    const int* __restrict__ cnt,
    float* __restrict__ stats, float* __restrict__ zp1) {
  const int t = threadIdx.x;
  if (blockIdx.x < NB_W) {
    __shared__ float s_ww2t[8][8];
    __shared__ float s_sc[8], s_sh[8];
    if (t < 64) { int c = t >> 3, h = t & 7; s_ww2t[c][h] = ww2[h*8+c]; }
    if (t < 8)  { s_sc[t] = stats[F_Y1 + t]; s_sh[t] = stats[F_Y1 + 8 + t]; }
    __syncthreads();
    const long nkg = (long)blockIdx.x * 256 + t;
    bf16x8 yv = *(const bf16x8*)&Y1[nkg * 8];
    float a[8];
    #pragma unroll
    for (int c = 0; c < 8; c++)
      a[c] = fmaxf(fmaf(s_sc[c], bfs2f(yv[c]), s_sh[c]), 0.f);
    float y2[8];
    #pragma unroll
    for (int h = 0; h < 8; h++) y2[h] = wb2[h];
    #pragma unroll
    for (int c = 0; c < 8; c++)
      #pragma unroll
      for (int h = 0; h < 8; h++) y2[h] = fmaf(s_ww2t[c][h], a[c], y2[h]);
    const int slot = blockIdx.x & 63;
    float* su = stats + P_Y2 + slot * 16;
    #pragma unroll
    for (int h = 0; h < 8; h++) wave_stat(y2[h], su, su + 8, h);
    return;
  }
  // ---- f-path: zp1 = feats @ fw1^T + fb1 (MFMA), weighted stats(z1) ----
  __shared__ __align__(16) bf16 s_A[64 * 72];
  __shared__ float s_sum[64], s_sq[64];
  const int fblk = blockIdx.x - NB_W;
  const int p0 = fblk * 64;
  if (t < 64) { s_sum[t] = 0.f; s_sq[t] = 0.f; }
  for (int r = 0; r < 16; r++) {
    int e = r * 256 + t;
    int p = e >> 6, c = e & 63;
    int gp = p0 + p;
    float v = (gp < NPTS) ? feats[(size_t)gp*64 + c] : 0.f;
    s_A[p * 72 + c] = __float2bfloat16(v);
  }
  __syncthreads();
  const int wv = t >> 6, lane = t & 63, pt = lane & 15, kq = lane >> 4;
  for (int nt = 0; nt < 4; nt++) {
    f32x4 acc = {0.f, 0.f, 0.f, 0.f};
    int h = nt * 16 + pt;
    #pragma unroll
    for (int ks = 0; ks < 2; ks++) {
      bf16x8 av = *(const bf16x8*)&s_A[(wv*16 + pt) * 72 + ks*32 + kq*8];
      float4 b0 = *(const float4*)(fw1 + h*64 + ks*32 + kq*8);
      float4 b1 = *(const float4*)(fw1 + h*64 + ks*32 + kq*8 + 4);
      bf16x8 bv;
      bv[0]=f2bfs(b0.x); bv[1]=f2bfs(b0.y); bv[2]=f2bfs(b0.z); bv[3]=f2bfs(b0.w);
      bv[4]=f2bfs(b1.x); bv[5]=f2bfs(b1.y); bv[6]=f2bfs(b1.z); bv[7]=f2bfs(b1.w);
      acc = __builtin_amdgcn_mfma_f32_16x16x32_bf16(av, bv, acc, 0, 0, 0);
    }
    float bias = fb1[h];
    float ss = 0.f, qq = 0.f;
    #pragma unroll
    for (int r = 0; r < 4; r++) {
      int gp = p0 + wv*16 + kq*4 + r;
      float z = acc[r] + bias;
      if (gp < NPTS) {
        zp1[(size_t)gp*64 + h] = z;
        float w = (float)cnt[gp];
        ss += w * z; qq += w * z * z;
      }
    }
    ss += __shfl_xor(ss, 16); ss += __shfl_xor(ss, 32);
    qq += __shfl_xor(qq, 16); qq += __shfl_xor(qq, 32);
    if (lane < 16) { atomicAdd(&s_sum[h], ss); atomicAdd(&s_sq[h], qq); }
  }
  __syncthreads();
  if (t < 64) {
    int slot = blockIdx.x & 63;
    atomicAdd(stats + P_Z1 + slot*128 + t, s_sum[t]);
    atomicAdd(stats + P_Z1 + slot*128 + 64 + t, s_sq[t]);
  }
}

// ================= K3: w-path y3 stats + f-path conv2 (zp2) =================
__global__ __launch_bounds__(256) void k3(
    const bf16* __restrict__ Y1,
    const float* __restrict__ ww2, const float* __restrict__ wb2,
    const float* __restrict__ ww3, const float* __restrict__ wb3,
    const float* __restrict__ zp1, const float* __restrict__ fw2, const float* __restrict__ fb2,
    const int* __restrict__ cnt,
    float* __restrict__ stats, float* __restrict__ zp2) {
  const int t = threadIdx.x;
  if (blockIdx.x < NB_W) {
    __shared__ float s_ww2t[8][8];
    __shared__ float s_ww3t[8][16];
    __shared__ float s_sc1[8], s_sh1[8], s_sc2[8], s_sh2[8];
    if (t < 64)  { int c = t >> 3, h = t & 7; s_ww2t[c][h] = ww2[h*8+c]; }
    if (t < 128) { int h = t >> 4, m = t & 15; s_ww3t[h][m] = ww3[m*8+h]; }
    if (t < 8)  { s_sc1[t] = stats[F_Y1 + t]; s_sh1[t] = stats[F_Y1 + 8 + t]; }
    if (t >= 8 && t < 16) { s_sc2[t-8] = stats[F_Y2 + (t-8)]; s_sh2[t-8] = stats[F_Y2 + 8 + (t-8)]; }
    __syncthreads();
    const long nkg = (long)blockIdx.x * 256 + t;
    bf16x8 yv = *(const bf16x8*)&Y1[nkg * 8];
    float a[8];
    #pragma unroll
    for (int c = 0; c < 8; c++)
      a[c] = fmaxf(fmaf(s_sc1[c], bfs2f(yv[c]), s_sh1[c]), 0.f);
    float y2[8];
    #pragma unroll
    for (int h = 0; h < 8; h++) y2[h] = wb2[h];
    #pragma unroll
    for (int c = 0; c < 8; c++)
      #pragma unroll
      for (int h = 0; h < 8; h++) y2[h] = fmaf(s_ww2t[c][h], a[c], y2[h]);
    float a2w[8];
    #pragma unroll
    for (int h = 0; h < 8; h++) a2w[h] = fmaxf(fmaf(s_sc2[h], y2[h], s_sh2[h]), 0.f);
    float y3[16];
    #pragma unroll
    for (int m = 0; m < 16; m++) y3[m] = wb3[m];
    #pragma unroll
    for (int h = 0; h < 8; h++)
      #pragma unroll
      for (int m = 0; m < 16; m++) y3[m] = fmaf(s_ww3t[h][m], a2w[h], y3[m]);
    const int slot = blockIdx.x & 63;
    float* su = stats + P_Y3 + slot * 32;
    #pragma unroll
    for (int m = 0; m < 16; m++) wave_stat(y3[m], su, su + 16, m);
    return;
  }
  // ---- f-path: zp2 = relu(bn(zp1)) @ fw2^T + fb2 (MFMA), weighted stats(z2) ----
  __shared__ __align__(16) bf16 s_A[64 * 72];
  __shared__ float s_sum[64], s_sq[64];
  __shared__ float s_sc[64], s_sh[64];
  const int fblk = blockIdx.x - NB_W;
  const int p0 = fblk * 64;
  if (t < 64) { s_sum[t] = 0.f; s_sq[t] = 0.f; s_sc[t] = stats[F_Z1 + t]; s_sh[t] = stats[F_Z1 + 64 + t]; }
  __syncthreads();
  for (int r = 0; r < 16; r++) {
    int e = r * 256 + t;
    int p = e >> 6, c = e & 63;
    int gp = p0 + p;
    float v = 0.f;
    if (gp < NPTS) v = fmaxf(fmaf(s_sc[c], zp1[(size_t)gp*64 + c], s_sh[c]), 0.f);
    s_A[p * 72 + c] = __float2bfloat16(v);
  }
  __syncthreads();
  const int wv = t >> 6, lane = t & 63, pt = lane & 15, kq = lane >> 4;
  for (int nt = 0; nt < 4; nt++) {
    f32x4 acc = {0.f, 0.f, 0.f, 0.f};
    int h = nt * 16 + pt;
    #pragma unroll
    for (int ks = 0; ks < 2; ks++) {
      bf16x8 av = *(const bf16x8*)&s_A[(wv*16 + pt) * 72 + ks*32 + kq*8];
      float4 b0 = *(const float4*)(fw2 + h*64 + ks*32 + kq*8);
      float4 b1 = *(const float4*)(fw2 + h*64 + ks*32 + kq*8 + 4);
      bf16x8 bv;
      bv[0]=f2bfs(b0.x); bv[1]=f2bfs(b0.y); bv[2]=f2bfs(b0.z); bv[3]=f2bfs(b0.w);
      bv[4]=f2bfs(b1.x); bv[5]=f2bfs(b1.y); bv[6]=f2bfs(b1.z); bv[7]=f2bfs(b1.w);
      acc = __builtin_amdgcn_mfma_f32_16x16x32_bf16(av, bv, acc, 0, 0, 0);
    }
    float bias = fb2[h];
    float ss = 0.f, qq = 0.f;
    #pragma unroll
    for (int r = 0; r < 4; r++) {
      int gp = p0 + wv*16 + kq*4 + r;
      float z = acc[r] + bias;
      if (gp < NPTS) {
        zp2[(size_t)gp*64 + h] = z;
        float w = (float)cnt[gp];
        ss += w * z; qq += w * z * z;
      }
    }
    ss += __shfl_xor(ss, 16); ss += __shfl_xor(ss, 32);
    qq += __shfl_xor(qq, 16); qq += __shfl_xor(qq, 32);
    if (lane < 16) { atomicAdd(&s_sum[h], ss); atomicAdd(&s_sq[h], qq); }
  }
  __syncthreads();
  if (t < 64) {
    int slot = blockIdx.x & 63;
    atomicAdd(stats + P_Z2 + slot*128 + t, s_sum[t]);
    atomicAdd(stats + P_Z2 + slot*128 + 64 + t, s_sq[t]);
  }
}

// ================= K3b: a2 = bf16(relu(bn(zp2))) [NPTS][64] =================
__global__ __launch_bounds__(256) void k3b(
    const float* __restrict__ zp2, const float* __restrict__ stats, bf16* __restrict__ a2) {
  long e = ((long)blockIdx.x * 256 + threadIdx.x) * 4;
  int c = (int)(e & 63);
  float4 v = *(const float4*)(zp2 + e);
  bf16x4 o;
  o[0] = f2bfs(fmaxf(fmaf(stats[F_Z2 + c+0], v.x, stats[F_Z2 + 64 + c+0]), 0.f));
  o[1] = f2bfs(fmaxf(fmaf(stats[F_Z2 + c+1], v.y, stats[F_Z2 + 64 + c+1]), 0.f));
  o[2] = f2bfs(fmaxf(fmaf(stats[F_Z2 + c+2], v.z, stats[F_Z2 + 64 + c+2]), 0.f));
  o[3] = f2bfs(fmaxf(fmaf(stats[F_Z2 + c+3], v.w, stats[F_Z2 + 64 + c+3]), 0.f));
  *(bf16x4*)&a2[e] = o;
}

// ================= K4: fused w-recompute + a2 gather + new + linear (MFMA) + lin stats =================
__global__ __launch_bounds__(256) void k4(
    const bf16* __restrict__ Y1, const int* __restrict__ knn,
    const float* __restrict__ ww2, const float* __restrict__ wb2,
    const float* __restrict__ ww3, const float* __restrict__ wb3,
    const bf16* __restrict__ a2, const bf16* __restrict__ lwb, const float* __restrict__ linb,
    float* __restrict__ stats, float* __restrict__ outp) {
  __shared__ int s_idx[256];
  __shared__ float s_ww2t[8][8];
  __shared__ float s_ww3t[8][16];
  __shared__ float s_scy1[8], s_shy1[8], s_scy2[8], s_shy2[8];
  __shared__ float s_scy3[16], s_shy3[16];
  __shared__ __align__(16) bf16 s_w[16 * 392];     // [p][k][m]: p*392 + k*24 + m
  __shared__ __align__(16) bf16 s_new[16 * 1032];  // [p][i-swizzled], row stride 1032
  const int t = threadIdx.x;
  const long base = (long)blockIdx.x * 256;
  s_idx[t] = knn[base + t];
  if (t < 64)  { int c = t >> 3, h = t & 7; s_ww2t[c][h] = ww2[h*8+c]; }
  if (t < 128) { int h = t >> 4, m = t & 15; s_ww3t[h][m] = ww3[m*8+h]; }
  if (t < 8)  { s_scy1[t] = stats[F_Y1 + t]; s_shy1[t] = stats[F_Y1 + 8 + t]; }
  if (t >= 8 && t < 16) { s_scy2[t-8] = stats[F_Y2 + (t-8)]; s_shy2[t-8] = stats[F_Y2 + 8 + (t-8)]; }
  if (t >= 16 && t < 32) { s_scy3[t-16] = stats[F_Y3 + (t-16)]; s_shy3[t-16] = stats[F_Y3 + 16 + (t-16)]; }
  __syncthreads();

  // ---- phase 1: recompute w-path for this thread's nk ----
  {
    const long nkg = base + t;
    bf16x8 yv = *(const bf16x8*)&Y1[nkg * 8];
    float a[8];
    #pragma unroll
    for (int c = 0; c < 8; c++)
      a[c] = fmaxf(fmaf(s_scy1[c], bfs2f(yv[c]), s_shy1[c]), 0.f);
    float y2[8];
    #pragma unroll
    for (int h = 0; h < 8; h++) y2[h] = wb2[h];
    #pragma unroll
    for (int c = 0; c < 8; c++)
      #pragma unroll
      for (int h = 0; h < 8; h++) y2[h] = fmaf(s_ww2t[c][h], a[c], y2[h]);
    float a2w[8];
    #pragma unroll
    for (int h = 0; h < 8; h++) a2w[h] = fmaxf(fmaf(s_scy2[h], y2[h], s_shy2[h]), 0.f);
    float y3[16];
    #pragma unroll
    for (int m = 0; m < 16; m++) y3[m] = wb3[m];
    #pragma unroll
    for (int h = 0; h < 8; h++)
      #pragma unroll
      for (int m = 0; m < 16; m++) y3[m] = fmaf(s_ww3t[h][m], a2w[h], y3[m]);
    const int p = t >> 4, k = t & 15;
    #pragma unroll
    for (int mp = 0; mp < 8; mp++) {
      float w0 = fmaxf(fmaf(s_scy3[2*mp],   y3[2*mp],   s_shy3[2*mp]),   0.f);
      float w1 = fmaxf(fmaf(s_scy3[2*mp+1], y3[2*mp+1], s_shy3[2*mp+1]), 0.f);
      __hip_bfloat162 pk; pk.x = __float2bfloat16(w0); pk.y = __float2bfloat16(w1);
      *(__hip_bfloat162*)&s_w[p*392 + k*24 + 2*mp] = pk;
    }
  }
  __syncthreads();

  // ---- phase 2: new[p][h*16+m] = sum_k f[h][k]*w[m][k], f gathered from a2 (pre-activated bf16) ----
  {
    const int p = t >> 4, l = t & 15;
    float acc[4][16];
    #pragma unroll
    for (int hj = 0; hj < 4; hj++)
      #pragma unroll
      for (int m = 0; m < 16; m++) acc[hj][m] = 0.f;
    #pragma unroll 4
    for (int k = 0; k < 16; k++) {
      int idx = s_idx[(p << 4) + k];
      bf16x4 zf = *(const bf16x4*)(a2 + (size_t)idx*64 + (l << 2));
      float f0 = bfs2f(zf[0]);
      float f1 = bfs2f(zf[1]);
      float f2 = bfs2f(zf[2]);
      float f3 = bfs2f(zf[3]);
      #pragma unroll
      for (int mp = 0; mp < 8; mp++) {
        __hip_bfloat162 wp = *(const __hip_bfloat162*)&s_w[p*392 + k*24 + 2*mp];
        float w0 = __bfloat162float(wp.x), w1 = __bfloat162float(wp.y);
        acc[0][2*mp]   = fmaf(f0, w0, acc[0][2*mp]);   acc[0][2*mp+1] = fmaf(f0, w1, acc[0][2*mp+1]);
        acc[1][2*mp]   = fmaf(f1, w0, acc[1][2*mp]);   acc[1][2*mp+1] = fmaf(f1, w1, acc[1][2*mp+1]);
        acc[2][2*mp]   = fmaf(f2, w0, acc[2][2*mp]);   acc[2][2*mp+1] = fmaf(f2, w1, acc[2][2*mp+1]);
        acc[3][2*mp]   = fmaf(f3, w0, acc[3][2*mp]);   acc[3][2*mp+1] = fmaf(f3, w1, acc[3][2*mp+1]);
      }
    }
    const int swz = (l & 7) * 8;
    #pragma unroll
    for (int hj = 0; hj < 4; hj++)
      #pragma unroll
      for (int mp = 0; mp < 8; mp++) {
        int v = hj*16 + 2*mp;
        int phys = (l << 6) + (v ^ swz);
        __hip_bfloat162 pk;
        pk.x = __float2bfloat16(acc[hj][2*mp]); pk.y = __float2bfloat16(acc[hj][2*mp+1]);
        *(__hip_bfloat162*)&s_new[p*1032 + phys] = pk;
      }
  }
  __syncthreads();

  // ---- phase 3: out = new(16x1024) @ lwb^T(1024x64) + linb via MFMA ----
  {
    const int wv = t >> 6, lane = t & 63, pt = lane & 15, kq = lane >> 4;
    const int j = wv * 16 + pt;
    const bf16* lwrow = lwb + j * 1024;
    f32x4 acc = {0.f, 0.f, 0.f, 0.f};
    #pragma unroll 8
    for (int ks = 0; ks < 32; ks++) {
      int i = ks*32 + kq*8;
      int l2 = i >> 6, v = i & 63;
      int phys = (l2 << 6) + (v ^ ((l2 & 7) * 8));
      bf16x8 av = *(const bf16x8*)&s_new[pt*1032 + phys];
      bf16x8 bv = *(const bf16x8*)(lwrow + i);
      acc = __builtin_amdgcn_mfma_f32_16x16x32_bf16(av, bv, acc, 0, 0, 0);
    }
    float bj = linb[j];
    float ss = 0.f, qq = 0.f;
    #pragma unroll
    for (int r = 0; r < 4; r++) {
      int gp = (int)(blockIdx.x * 16) + kq*4 + r;
      float val = acc[r] + bj;
      outp[(size_t)gp*64 + j] = val;
      ss += val; qq += val * val;
    }
    ss += __shfl_xor(ss, 16); ss += __shfl_xor(ss, 32);
    qq += __shfl_xor(qq, 16); qq += __shfl_xor(qq, 32);
    if (lane < 16) {
      int slot = blockIdx.x & 63;
      atomicAdd(stats + P_LIN + slot*128 + j, ss);
      atomicAdd(stats + P_LIN + slot*128 + 64 + j, qq);
    }
  }
}

// ================= K6: final BN + ReLU in-place on d_out =================
__global__ __launch_bounds__(256) void k6(float* __restrict__ outp, const float* __restrict__ stats) {
  long e = (long)blockIdx.x * 256 + threadIdx.x;
  int j = (int)(e & 63);
  float sc = stats[F_LIN + j], sh = stats[F_LIN + 64 + j];
  float v = outp[e];
  outp[e] = fmaxf(fmaf(sc, v, sh), 0.f);
}

// signature if workspace too small: absmax ~= ws_size in MB
__global__ void k_wsfail(float* outp, float mb) {
  outp[threadIdx.x] = -mb;
}

extern "C" void kernel_launch(void* const* d_in, const int* in_sizes, int n_in,
                              void* d_out, int out_size, void* d_ws, size_t ws_size,
                              hipStream_t stream) {
  const float* xyz  = (const float*)d_in[0];
  const float* cov  = (const float*)d_in[1];
  const float* feats= (const float*)d_in[2];
  const int*   knn  = (const int*)d_in[3];
  const float* fw1  = (const float*)d_in[4];
  const float* fb1  = (const float*)d_in[5];
  const float* fg1  = (const float*)d_in[6];
  const float* fbe1 = (const float*)d_in[7];
  const float* fw2  = (const float*)d_in[8];
  const float* fb2  = (const float*)d_in[9];
  const float* fg2  = (const float*)d_in[10];
  const float* fbe2 = (const float*)d_in[11];
  const float* ww1  = (const float*)d_in[12];
  const float* wb1  = (const float*)d_in[13];
  const float* wg1  = (const float*)d_in[14];
  const float* wbe1 = (const float*)d_in[15];
  const float* ww2  = (const float*)d_in[16];
  const float* wb2  = (const float*)d_in[17];
  const float* wg2  = (const float*)d_in[18];
  const float* wbe2 = (const float*)d_in[19];
  const float* ww3  = (const float*)d_in[20];
  const float* wb3  = (const float*)d_in[21];
  const float* wg3  = (const float*)d_in[22];
  const float* wbe3 = (const float*)d_in[23];
  const float* linw = (const float*)d_in[24];
  const float* linb = (const float*)d_in[25];
  const float* bng  = (const float*)d_in[26];
  const float* bnb  = (const float*)d_in[27];

  float* outp = (float*)d_out;
  if (ws_size < WS_NEED) {
    hipLaunchKernelGGL(k_wsfail, dim3(1), dim3(256), 0, stream, outp, (float)(ws_size >> 20));
    return;
  }
  char* ws = (char*)d_ws;
  float* stats = (float*)ws;
  int*   cnt   = (int*)(ws + CNT_BYTE);
  bf16*  Y1    = (bf16*)(ws + OFS_Y1);
  float* zp1   = (float*)(ws + OFS_ZP1);
  bf16*  a2    = (bf16*)(ws + OFS_ZP1);   // overlays zp1 (dead after k3)
  float* zp2   = (float*)(ws + OFS_ZP2);
  float* P     = (float*)(ws + OFS_P);
  bf16*  lwb   = (bf16*)(ws + OFS_LWB);

  hipMemsetAsync(d_ws, 0, ZERO_BYTES, stream);
  hipLaunchKernelGGL(k0, dim3(NB_P + 64), dim3(256), 0, stream,
                     xyz, cov, feats, linw, P, lwb);
  hipLaunchKernelGGL(k1, dim3(NB_W), dim3(256), 0, stream,
                     P, knn, ww1, wb1, stats, cnt, Y1);
  hipLaunchKernelGGL(kfin, dim3(1), dim3(64), 0, stream, stats,
                     P_Y1, 8, F_Y1, wg1, wbe1, (float)NKTOT,
                     P_Y1, 8, F_Y1, wg1, wbe1, (float)NKTOT);
  hipLaunchKernelGGL(k2, dim3(NB_W + NB_F), dim3(256), 0, stream,
                     Y1, ww2, wb2, feats, fw1, fb1, cnt, stats, zp1);
  hipLaunchKernelGGL(kfin, dim3(2), dim3(64), 0, stream, stats,
                     P_Y2, 8, F_Y2, wg2, wbe2, (float)NKTOT,
                     P_Z1, 64, F_Z1, fg1, fbe1, (float)NKTOT);
  hipLaunchKernelGGL(k3, dim3(NB_W + NB_F), dim3(256), 0, stream,
                     Y1, ww2, wb2, ww3, wb3, zp1, fw2, fb2, cnt, stats, zp2);
  hipLaunchKernelGGL(kfin, dim3(2), dim3(64), 0, stream, stats,
                     P_Y3, 16, F_Y3, wg3, wbe3, (float)NKTOT,
                     P_Z2, 64, F_Z2, fg2, fbe2, (float)NKTOT);
  hipLaunchKernelGGL(k3b, dim3(6250), dim3(256), 0, stream, zp2, stats, a2);
  hipLaunchKernelGGL(k4, dim3(NB_W), dim3(256), 0, stream,
                     Y1, knn, ww2, wb2, ww3, wb3, a2, lwb, linb, stats, outp);
  hipLaunchKernelGGL(kfin, dim3(1), dim3(64), 0, stream, stats,
                     P_LIN, 64, F_LIN, bng, bnb, (float)NPTS,
                     P_LIN, 64, F_LIN, bng, bnb, (float)NPTS);
  hipLaunchKernelGGL(k6, dim3(25000), dim3(256), 0, stream, outp, stats);
}

// Round 4
// 595.049 us; speedup vs baseline: 1.6944x; 1.6780x over previous
//
#include <hip/hip_runtime.h>
#include <hip/hip_bf16.h>

typedef __hip_bfloat16 bf16;
typedef __attribute__((ext_vector_type(8))) short bf16x8;
typedef __attribute__((ext_vector_type(4))) short bf16x4;
typedef __attribute__((ext_vector_type(4))) float f32x4;

#define NPTS 100000
#define KNN 16
#define NKTOT 1600000
#define NB_W 6250      // w-path blocks (256 nk each)
#define NB_F 1563      // f-path blocks (64 points each, MFMA)
#define NB_P 391       // P-pack blocks (256 points each)

// ---- stats region: finalized BN scale/shift (float offsets within ws) ----
#define F_Y1 28672
#define F_Z1 28688
#define F_Y2 28816
#define F_Z2 28832
#define F_Y3 28960
#define F_LIN 28992
#define CNT_BYTE 131072ull
#define ZERO_BYTES 531072ull   // stats + cnt

// ---- per-block stat partials (float offsets within part base) ----
#define Q_Y1 0            // [6250][16]
#define Q_Y2 100000       // [6250][16]
#define Q_Y3 200000       // [6250][32]
#define Q_LIN 400000      // [6250][128]
#define Q_Z1 1200000      // [1563][128]
#define Q_Z2 1400064      // [1563][128]

// ---- big buffers (byte offsets, MiB-aligned) ----
#define OFS_Y1   (1ull<<20)    // Y1 bf16 [NKTOT][8]    25.6 MB (ends 26.6)
#define OFS_ZP1  (27ull<<20)   // zp1 fp32 [NPTS][64]   25.6 MB; a2 bf16 overlays later
#define OFS_ZP2  (53ull<<20)   // zp2 fp32 [NPTS][64]   25.6 MB (ends 78.6)
#define OFS_P    OFS_ZP2       // packed geometry overlays zp2 (dead before k3 writes)
#define OFS_PART (79ull<<20)   // partials 6.41 MB (ends 85.5)
#define OFS_LWB  (86ull<<20)   // lin_w bf16 [64][1024] 128 KB
#define WS_NEED  (OFS_LWB + 131072ull)   // ~86.2 MiB

__device__ inline float bfs2f(short s) {
  unsigned int u = ((unsigned int)(unsigned short)s) << 16;
  float f; __builtin_memcpy(&f, &u, 4); return f;
}
__device__ inline short f2bfs(float x) {
  bf16 h = __float2bfloat16(x);
  short s; __builtin_memcpy(&s, &h, 2); return s;
}

// wave-reduce (sum) of one value across 64 lanes; result valid on all lanes
__device__ inline float wred(float v) {
  #pragma unroll
  for (int o = 32; o > 0; o >>= 1) v += __shfl_xor(v, o);
  return v;
}

// ================= K0: pack geometry P[n]={xyz3,pad,nrm3,cov9} + lin_w->bf16 =================
__global__ __launch_bounds__(256) void k0(
    const float* __restrict__ xyz, const float* __restrict__ cov,
    const float* __restrict__ feats, const float* __restrict__ linw,
    float* __restrict__ P, bf16* __restrict__ lwb) {
  const int t = threadIdx.x;
  if (blockIdx.x >= NB_P) {
    int e = (blockIdx.x - NB_P) * 1024 + t * 4;
    if (e < 65536) {
      float4 v = *(const float4*)(linw + e);
      lwb[e+0] = __float2bfloat16(v.x); lwb[e+1] = __float2bfloat16(v.y);
      lwb[e+2] = __float2bfloat16(v.z); lwb[e+3] = __float2bfloat16(v.w);
    }
    return;
  }
  int n = blockIdx.x * 256 + t;
  if (n >= NPTS) return;
  float4 o0, o1, o2, o3;
  o0.x = xyz[n*3+0]; o0.y = xyz[n*3+1]; o0.z = xyz[n*3+2]; o0.w = 0.f;
  o1.x = feats[(size_t)n*64+3]; o1.y = feats[(size_t)n*64+4]; o1.z = feats[(size_t)n*64+5];
  const float* cv = cov + (size_t)n*9;
  o1.w = cv[0];
  o2.x = cv[1]; o2.y = cv[2]; o2.z = cv[3]; o2.w = cv[4];
  o3.x = cv[5]; o3.y = cv[6]; o3.z = cv[7]; o3.w = cv[8];
  float* pr = P + (size_t)n*16;
  *(float4*)(pr+0) = o0; *(float4*)(pr+4) = o1;
  *(float4*)(pr+8) = o2; *(float4*)(pr+12) = o3;
}

// ================= K1: packed gather + geometry + w-conv1 + cnt histogram =================
__global__ __launch_bounds__(256) void k1(
    const float* __restrict__ P, const int* __restrict__ knn,
    const float* __restrict__ ww1, const float* __restrict__ wb1,
    float* __restrict__ part, int* __restrict__ cnt, bf16* __restrict__ Y1) {
  __shared__ float s_P[256][16];
  __shared__ float s_ww1t[14][8];
  __shared__ float s_ws[4][16];
  const int t = threadIdx.x;
  const long base = (long)blockIdx.x * 256;
  if (t < 112) { int c = t >> 3, h = t & 7; s_ww1t[c][h] = ww1[h * 14 + c]; }
  const int idx = knn[base + t];
  atomicAdd(&cnt[idx], 1);
  const float* pr = P + (size_t)idx * 16;
  float4 r0 = *(const float4*)(pr+0);
  float4 r1 = *(const float4*)(pr+4);
  float4 r2 = *(const float4*)(pr+8);
  float4 r3 = *(const float4*)(pr+12);
  *(float4*)&s_P[t][0] = r0; *(float4*)&s_P[t][4] = r1;
  *(float4*)&s_P[t][8] = r2; *(float4*)&s_P[t][12] = r3;
  __syncthreads();
  const int b = t & ~15;   // neighbor-0 row of this thread's point
  float lx = r0.x - s_P[b][0], ly = r0.y - s_P[b][1], lz = r0.z - s_P[b][2];
  float nmx = s_P[b][4], nmy = s_P[b][5], nmz = s_P[b][6];   // n_miu
  float nax = r1.x, nay = r1.y, naz = r1.z;                  // n_alpha (own)
  float t9v = sqrtf(lx*lx + ly*ly + lz*lz);
  float rn = 1.0f / fmaxf(t9v, 1e-12f);
  float rx = lx*rn, ry = ly*rn, rz = lz*rn;
  float t2v = nmx*rx + nmy*ry + nmz*rz;
  float vx = nmx - t2v*rx, vy = nmy - t2v*ry, vz = nmz - t2v*rz;
  float vn = 1.0f / fmaxf(sqrtf(vx*vx+vy*vy+vz*vz), 1e-12f);
  vx *= vn; vy *= vn; vz *= vn;
  float wxv = ry*vz - rz*vy, wyv = rz*vx - rx*vz, wzv = rx*vy - ry*vx;
  float wn = 1.0f / fmaxf(sqrtf(wxv*wxv+wyv*wyv+wzv*wzv), 1e-12f);
  wxv *= wn; wyv *= wn; wzv *= wn;
  float t1v = nax*nmx + nay*nmy + naz*nmz;
  float t3v = rx*nax + ry*nay + rz*naz;
  float t4v = lx*nmx + ly*nmy + lz*nmz;
  float t6v = nax*vx + nay*vy + naz*vz;
  float t7v = nax*wxv + nay*wyv + naz*wzv;
  float cxx = nay*nmz - naz*nmy, cyy = naz*nmx - nax*nmz, czz = nax*nmy - nay*nmx;
  float t8v = lx*cxx + ly*cyy + lz*czz;
  float q0 = r1.w*lx + r2.x*ly + r2.y*lz;
  float q1 = r2.z*lx + r2.w*ly + r3.x*lz;
  float q2 = r3.y*lx + r3.z*ly + r3.w*lz;
  float s1v = lx*q0 + ly*q1 + lz*q2;
  float p0 = s_P[b][7]*lx  + s_P[b][8]*ly  + s_P[b][9]*lz;
  float p1 = s_P[b][10]*lx + s_P[b][11]*ly + s_P[b][12]*lz;
  float p2 = s_P[b][13]*lx + s_P[b][14]*ly + s_P[b][15]*lz;
  float s2v = lx*p0 + ly*p1 + lz*p2;
  float win[14] = {lx, ly, lz, t1v, t2v, t3v, t4v, t3v, t6v, t7v, t8v, t9v, s1v, s2v};
  float y[8];
  #pragma unroll
  for (int h = 0; h < 8; h++) y[h] = wb1[h];
  #pragma unroll
  for (int c = 0; c < 14; c++) {
    float x = win[c];
    #pragma unroll
    for (int h = 0; h < 8; h++) y[h] = fmaf(s_ww1t[c][h], x, y[h]);
  }
  const long nkg = base + t;
  bf16x8 pk;
  #pragma unroll
  for (int h = 0; h < 8; h++) pk[h] = f2bfs(y[h]);
  *(bf16x8*)&Y1[nkg * 8] = pk;
  // per-block stats: wave shfl-reduce -> LDS -> plain store
  const int w = t >> 6, lane = t & 63;
  #pragma unroll
  for (int h = 0; h < 8; h++) {
    float s = wred(y[h]);
    float q = wred(y[h] * y[h]);
    if (lane == 0) { s_ws[w][h] = s; s_ws[w][8 + h] = q; }
  }
  __syncthreads();
  if (t < 16)
    part[Q_Y1 + blockIdx.x * 16 + t] = s_ws[0][t] + s_ws[1][t] + s_ws[2][t] + s_ws[3][t];
}

// ================= kredfin: reduce per-block partials -> BN scale/shift (two layers) =================
__global__ __launch_bounds__(256) void kredfin(
    const float* __restrict__ part, float* __restrict__ stats,
    int qA, int nA, int cA, const float* gA, const float* beA, float mA, int fA,
    int qB, int nB, int cB, const float* gB, const float* beB, float mB, int fB) {
  int c = blockIdx.x;
  const float* p; int nblk, C, f; const float *g, *be; float M;
  if (c < cA) { p = part + qA; nblk = nA; C = cA; g = gA; be = beA; M = mA; f = fA; }
  else { c -= cA; p = part + qB; nblk = nB; C = cB; g = gB; be = beB; M = mB; f = fB; }
  const int t = threadIdx.x;
  float s = 0.f, q = 0.f;
  for (int b = t; b < nblk; b += 256) {
    s += p[(size_t)b * 2 * C + c];
    q += p[(size_t)b * 2 * C + C + c];
  }
  s = wred(s); q = wred(q);
  __shared__ float rs[4], rq[4];
  const int w = t >> 6;
  if ((t & 63) == 0) { rs[w] = s; rq[w] = q; }
  __syncthreads();
  if (t == 0) {
    s = rs[0] + rs[1] + rs[2] + rs[3];
    q = rq[0] + rq[1] + rq[2] + rq[3];
    float mean = s / M;
    float var = q / M - mean * mean;
    float scale = g[c] / sqrtf(var + 1e-5f);
    stats[f + c] = scale;
    stats[f + C + c] = be[c] - mean * scale;
  }
}

// ================= K2: w-path y2 stats + f-path conv1 (zp1) =================
__global__ __launch_bounds__(256) void k2(
    const bf16* __restrict__ Y1, const float* __restrict__ ww2, const float* __restrict__ wb2,
    const float* __restrict__ feats, const float* __restrict__ fw1, const float* __restrict__ fb1,
    const int* __restrict__ cnt, const float* __restrict__ stats,
    float* __restrict__ part, float* __restrict__ zp1) {
  const int t = threadIdx.x;
  if (blockIdx.x < NB_W) {
    __shared__ float s_ww2t[8][8];
    __shared__ float s_sc[8], s_sh[8];
    __shared__ float s_ws[4][16];
    if (t < 64) { int c = t >> 3, h = t & 7; s_ww2t[c][h] = ww2[h*8+c]; }
    if (t < 8)  { s_sc[t] = stats[F_Y1 + t]; s_sh[t] = stats[F_Y1 + 8 + t]; }
    __syncthreads();
    const long nkg = (long)blockIdx.x * 256 + t;
    bf16x8 yv = *(const bf16x8*)&Y1[nkg * 8];
    float a[8];
    #pragma unroll
    for (int c = 0; c < 8; c++)
      a[c] = fmaxf(fmaf(s_sc[c], bfs2f(yv[c]), s_sh[c]), 0.f);
    float y2[8];
    #pragma unroll
    for (int h = 0; h < 8; h++) y2[h] = wb2[h];
    #pragma unroll
    for (int c = 0; c < 8; c++)
      #pragma unroll
      for (int h = 0; h < 8; h++) y2[h] = fmaf(s_ww2t[c][h], a[c], y2[h]);
    const int w = t >> 6, lane = t & 63;
    #pragma unroll
    for (int h = 0; h < 8; h++) {
      float s = wred(y2[h]);
      float q = wred(y2[h] * y2[h]);
      if (lane == 0) { s_ws[w][h] = s; s_ws[w][8 + h] = q; }
    }
    __syncthreads();
    if (t < 16)
      part[Q_Y2 + blockIdx.x * 16 + t] = s_ws[0][t] + s_ws[1][t] + s_ws[2][t] + s_ws[3][t];
    return;
  }
  // ---- f-path: zp1 = feats @ fw1^T + fb1 (MFMA), weighted stats(z1) ----
  __shared__ __align__(16) bf16 s_A[64 * 72];
  __shared__ float s_sum[64], s_sq[64];
  const int fblk = blockIdx.x - NB_W;
  const int p0 = fblk * 64;
  if (t < 64) { s_sum[t] = 0.f; s_sq[t] = 0.f; }
  for (int r = 0; r < 16; r++) {
    int e = r * 256 + t;
    int p = e >> 6, c = e & 63;
    int gp = p0 + p;
    float v = (gp < NPTS) ? feats[(size_t)gp*64 + c] : 0.f;
    s_A[p * 72 + c] = __float2bfloat16(v);
  }
  __syncthreads();
  const int wv = t >> 6, lane = t & 63, pt = lane & 15, kq = lane >> 4;
  for (int nt = 0; nt < 4; nt++) {
    f32x4 acc = {0.f, 0.f, 0.f, 0.f};
    int h = nt * 16 + pt;
    #pragma unroll
    for (int ks = 0; ks < 2; ks++) {
      bf16x8 av = *(const bf16x8*)&s_A[(wv*16 + pt) * 72 + ks*32 + kq*8];
      float4 b0 = *(const float4*)(fw1 + h*64 + ks*32 + kq*8);
      float4 b1 = *(const float4*)(fw1 + h*64 + ks*32 + kq*8 + 4);
      bf16x8 bv;
      bv[0]=f2bfs(b0.x); bv[1]=f2bfs(b0.y); bv[2]=f2bfs(b0.z); bv[3]=f2bfs(b0.w);
      bv[4]=f2bfs(b1.x); bv[5]=f2bfs(b1.y); bv[6]=f2bfs(b1.z); bv[7]=f2bfs(b1.w);
      acc = __builtin_amdgcn_mfma_f32_16x16x32_bf16(av, bv, acc, 0, 0, 0);
    }
    float bias = fb1[h];
    float ss = 0.f, qq = 0.f;
    #pragma unroll
    for (int r = 0; r < 4; r++) {
      int gp = p0 + wv*16 + kq*4 + r;
      float z = acc[r] + bias;
      if (gp < NPTS) {
        zp1[(size_t)gp*64 + h] = z;
        float w = (float)cnt[gp];
        ss += w * z; qq += w * z * z;
      }
    }
    ss += __shfl_xor(ss, 16); ss += __shfl_xor(ss, 32);
    qq += __shfl_xor(qq, 16); qq += __shfl_xor(qq, 32);
    if (lane < 16) { atomicAdd(&s_sum[h], ss); atomicAdd(&s_sq[h], qq); }
  }
  __syncthreads();
  if (t < 128)
    part[Q_Z1 + fblk * 128 + t] = (t < 64) ? s_sum[t] : s_sq[t - 64];
}

// ================= K3: w-path y3 stats + f-path conv2 (zp2) =================
__global__ __launch_bounds__(256) void k3(
    const bf16* __restrict__ Y1,
    const float* __restrict__ ww2, const float* __restrict__ wb2,
    const float* __restrict__ ww3, const float* __restrict__ wb3,
    const float* __restrict__ zp1, const float* __restrict__ fw2, const float* __restrict__ fb2,
    const int* __restrict__ cnt, const float* __restrict__ stats,
    float* __restrict__ part, float* __restrict__ zp2) {
  const int t = threadIdx.x;
  if (blockIdx.x < NB_W) {
    __shared__ float s_ww2t[8][8];
    __shared__ float s_ww3t[8][16];
    __shared__ float s_sc1[8], s_sh1[8], s_sc2[8], s_sh2[8];
    __shared__ float s_ws[4][32];
    if (t < 64)  { int c = t >> 3, h = t & 7; s_ww2t[c][h] = ww2[h*8+c]; }
    if (t < 128) { int h = t >> 4, m = t & 15; s_ww3t[h][m] = ww3[m*8+h]; }
    if (t < 8)  { s_sc1[t] = stats[F_Y1 + t]; s_sh1[t] = stats[F_Y1 + 8 + t]; }
    if (t >= 8 && t < 16) { s_sc2[t-8] = stats[F_Y2 + (t-8)]; s_sh2[t-8] = stats[F_Y2 + 8 + (t-8)]; }
    __syncthreads();
    const long nkg = (long)blockIdx.x * 256 + t;
    bf16x8 yv = *(const bf16x8*)&Y1[nkg * 8];
    float a[8];
    #pragma unroll
    for (int c = 0; c < 8; c++)
      a[c] = fmaxf(fmaf(s_sc1[c], bfs2f(yv[c]), s_sh1[c]), 0.f);
    float y2[8];
    #pragma unroll
    for (int h = 0; h < 8; h++) y2[h] = wb2[h];
    #pragma unroll
    for (int c = 0; c < 8; c++)
      #pragma unroll
      for (int h = 0; h < 8; h++) y2[h] = fmaf(s_ww2t[c][h], a[c], y2[h]);
    float a2w[8];
    #pragma unroll
    for (int h = 0; h < 8; h++) a2w[h] = fmaxf(fmaf(s_sc2[h], y2[h], s_sh2[h]), 0.f);
    float y3[16];
    #pragma unroll
    for (int m = 0; m < 16; m++) y3[m] = wb3[m];
    #pragma unroll
    for (int h = 0; h < 8; h++)
      #pragma unroll
      for (int m = 0; m < 16; m++) y3[m] = fmaf(s_ww3t[h][m], a2w[h], y3[m]);
    const int w = t >> 6, lane = t & 63;
    #pragma unroll
    for (int m = 0; m < 16; m++) {
      float s = wred(y3[m]);
      float q = wred(y3[m] * y3[m]);
      if (lane == 0) { s_ws[w][m] = s; s_ws[w][16 + m] = q; }
    }
    __syncthreads();
    if (t < 32)
      part[Q_Y3 + blockIdx.x * 32 + t] = s_ws[0][t] + s_ws[1][t] + s_ws[2][t] + s_ws[3][t];
    return;
  }
  // ---- f-path: zp2 = relu(bn(zp1)) @ fw2^T + fb2 (MFMA), weighted stats(z2) ----
  __shared__ __align__(16) bf16 s_A[64 * 72];
  __shared__ float s_sum[64], s_sq[64];
  __shared__ float s_sc[64], s_sh[64];
  const int fblk = blockIdx.x - NB_W;
  const int p0 = fblk * 64;
  if (t < 64) { s_sum[t] = 0.f; s_sq[t] = 0.f; s_sc[t] = stats[F_Z1 + t]; s_sh[t] = stats[F_Z1 + 64 + t]; }
  __syncthreads();
  for (int r = 0; r < 16; r++) {
    int e = r * 256 + t;
    int p = e >> 6, c = e & 63;
    int gp = p0 + p;
    float v = 0.f;
    if (gp < NPTS) v = fmaxf(fmaf(s_sc[c], zp1[(size_t)gp*64 + c], s_sh[c]), 0.f);
    s_A[p * 72 + c] = __float2bfloat16(v);
  }
  __syncthreads();
  const int wv = t >> 6, lane = t & 63, pt = lane & 15, kq = lane >> 4;
  for (int nt = 0; nt < 4; nt++) {
    f32x4 acc = {0.f, 0.f, 0.f, 0.f};
    int h = nt * 16 + pt;
    #pragma unroll
    for (int ks = 0; ks < 2; ks++) {
      bf16x8 av = *(const bf16x8*)&s_A[(wv*16 + pt) * 72 + ks*32 + kq*8];
      float4 b0 = *(const float4*)(fw2 + h*64 + ks*32 + kq*8);
      float4 b1 = *(const float4*)(fw2 + h*64 + ks*32 + kq*8 + 4);
      bf16x8 bv;
      bv[0]=f2bfs(b0.x); bv[1]=f2bfs(b0.y); bv[2]=f2bfs(b0.z); bv[3]=f2bfs(b0.w);
      bv[4]=f2bfs(b1.x); bv[5]=f2bfs(b1.y); bv[6]=f2bfs(b1.z); bv[7]=f2bfs(b1.w);
      acc = __builtin_amdgcn_mfma_f32_16x16x32_bf16(av, bv, acc, 0, 0, 0);
    }
    float bias = fb2[h];
    float ss = 0.f, qq = 0.f;
    #pragma unroll
    for (int r = 0; r < 4; r++) {
      int gp = p0 + wv*16 + kq*4 + r;
      float z = acc[r] + bias;
      if (gp < NPTS) {
        zp2[(size_t)gp*64 + h] = z;
        float w = (float)cnt[gp];
        ss += w * z; qq += w * z * z;
      }
    }
    ss += __shfl_xor(ss, 16); ss += __shfl_xor(ss, 32);
    qq += __shfl_xor(qq, 16); qq += __shfl_xor(qq, 32);
    if (lane < 16) { atomicAdd(&s_sum[h], ss); atomicAdd(&s_sq[h], qq); }
  }
  __syncthreads();
  if (t < 128)
    part[Q_Z2 + fblk * 128 + t] = (t < 64) ? s_sum[t] : s_sq[t - 64];
}

// ================= K3b: a2 = bf16(relu(bn(zp2))) [NPTS][64] =================
__global__ __launch_bounds__(256) void k3b(
    const float* __restrict__ zp2, const float* __restrict__ stats, bf16* __restrict__ a2) {
  long e = ((long)blockIdx.x * 256 + threadIdx.x) * 4;
  int c = (int)(e & 63);
  float4 v = *(const float4*)(zp2 + e);
  bf16x4 o;
  o[0] = f2bfs(fmaxf(fmaf(stats[F_Z2 + c+0], v.x, stats[F_Z2 + 64 + c+0]), 0.f));
  o[1] = f2bfs(fmaxf(fmaf(stats[F_Z2 + c+1], v.y, stats[F_Z2 + 64 + c+1]), 0.f));
  o[2] = f2bfs(fmaxf(fmaf(stats[F_Z2 + c+2], v.z, stats[F_Z2 + 64 + c+2]), 0.f));
  o[3] = f2bfs(fmaxf(fmaf(stats[F_Z2 + c+3], v.w, stats[F_Z2 + 64 + c+3]), 0.f));
  *(bf16x4*)&a2[e] = o;
}

// ================= K4: fused w-recompute + a2 gather + new + linear (MFMA) + lin stats =================
__global__ __launch_bounds__(256) void k4(
    const bf16* __restrict__ Y1, const int* __restrict__ knn,
    const float* __restrict__ ww2, const float* __restrict__ wb2,
    const float* __restrict__ ww3, const float* __restrict__ wb3,
    const bf16* __restrict__ a2, const bf16* __restrict__ lwb, const float* __restrict__ linb,
    const float* __restrict__ stats, float* __restrict__ part, float* __restrict__ outp) {
  __shared__ int s_idx[256];
  __shared__ float s_ww2t[8][8];
  __shared__ float s_ww3t[8][16];
  __shared__ float s_scy1[8], s_shy1[8], s_scy2[8], s_shy2[8];
  __shared__ float s_scy3[16], s_shy3[16];
  __shared__ float s_ls[64], s_lq[64];
  __shared__ __align__(16) bf16 s_w[16 * 392];     // [p][k][m]: p*392 + k*24 + m
  __shared__ __align__(16) bf16 s_new[16 * 1032];  // [p][i-swizzled], row stride 1032
  const int t = threadIdx.x;
  const long base = (long)blockIdx.x * 256;
  s_idx[t] = knn[base + t];
  if (t < 64)  { int c = t >> 3, h = t & 7; s_ww2t[c][h] = ww2[h*8+c]; }
  if (t < 128) { int h = t >> 4, m = t & 15; s_ww3t[h][m] = ww3[m*8+h]; }
  if (t < 8)  { s_scy1[t] = stats[F_Y1 + t]; s_shy1[t] = stats[F_Y1 + 8 + t]; }
  if (t >= 8 && t < 16) { s_scy2[t-8] = stats[F_Y2 + (t-8)]; s_shy2[t-8] = stats[F_Y2 + 8 + (t-8)]; }
  if (t >= 16 && t < 32) { s_scy3[t-16] = stats[F_Y3 + (t-16)]; s_shy3[t-16] = stats[F_Y3 + 16 + (t-16)]; }
  __syncthreads();

  // ---- phase 1: recompute w-path for this thread's nk ----
  {
    const long nkg = base + t;
    bf16x8 yv = *(const bf16x8*)&Y1[nkg * 8];
    float a[8];
    #pragma unroll
    for (int c = 0; c < 8; c++)
      a[c] = fmaxf(fmaf(s_scy1[c], bfs2f(yv[c]), s_shy1[c]), 0.f);
    float y2[8];
    #pragma unroll
    for (int h = 0; h < 8; h++) y2[h] = wb2[h];
    #pragma unroll
    for (int c = 0; c < 8; c++)
      #pragma unroll
      for (int h = 0; h < 8; h++) y2[h] = fmaf(s_ww2t[c][h], a[c], y2[h]);
    float a2w[8];
    #pragma unroll
    for (int h = 0; h < 8; h++) a2w[h] = fmaxf(fmaf(s_scy2[h], y2[h], s_shy2[h]), 0.f);
    float y3[16];
    #pragma unroll
    for (int m = 0; m < 16; m++) y3[m] = wb3[m];
    #pragma unroll
    for (int h = 0; h < 8; h++)
      #pragma unroll
      for (int m = 0; m < 16; m++) y3[m] = fmaf(s_ww3t[h][m], a2w[h], y3[m]);
    const int p = t >> 4, k = t & 15;
    #pragma unroll
    for (int mp = 0; mp < 8; mp++) {
      float w0 = fmaxf(fmaf(s_scy3[2*mp],   y3[2*mp],   s_shy3[2*mp]),   0.f);
      float w1 = fmaxf(fmaf(s_scy3[2*mp+1], y3[2*mp+1], s_shy3[2*mp+1]), 0.f);
      __hip_bfloat162 pk; pk.x = __float2bfloat16(w0); pk.y = __float2bfloat16(w1);
      *(__hip_bfloat162*)&s_w[p*392 + k*24 + 2*mp] = pk;
    }
  }
  __syncthreads();

  // ---- phase 2: new[p][h*16+m] = sum_k f[h][k]*w[m][k], f gathered from a2 (bf16) ----
  {
    const int p = t >> 4, l = t & 15;
    float acc[4][16];
    #pragma unroll
    for (int hj = 0; hj < 4; hj++)
      #pragma unroll
      for (int m = 0; m < 16; m++) acc[hj][m] = 0.f;
    #pragma unroll 4
    for (int k = 0; k < 16; k++) {
      int idx = s_idx[(p << 4) + k];
      bf16x4 zf = *(const bf16x4*)(a2 + (size_t)idx*64 + (l << 2));
      float f0 = bfs2f(zf[0]);
      float f1 = bfs2f(zf[1]);
      float f2 = bfs2f(zf[2]);
      float f3 = bfs2f(zf[3]);
      #pragma unroll
      for (int mp = 0; mp < 8; mp++) {
        __hip_bfloat162 wp = *(const __hip_bfloat162*)&s_w[p*392 + k*24 + 2*mp];
        float w0 = __bfloat162float(wp.x), w1 = __bfloat162float(wp.y);
        acc[0][2*mp]   = fmaf(f0, w0, acc[0][2*mp]);   acc[0][2*mp+1] = fmaf(f0, w1, acc[0][2*mp+1]);
        acc[1][2*mp]   = fmaf(f1, w0, acc[1][2*mp]);   acc[1][2*mp+1] = fmaf(f1, w1, acc[1][2*mp+1]);
        acc[2][2*mp]   = fmaf(f2, w0, acc[2][2*mp]);   acc[2][2*mp+1] = fmaf(f2, w1, acc[2][2*mp+1]);
        acc[3][2*mp]   = fmaf(f3, w0, acc[3][2*mp]);   acc[3][2*mp+1] = fmaf(f3, w1, acc[3][2*mp+1]);
      }
    }
    const int swz = (l & 7) * 8;
    #pragma unroll
    for (int hj = 0; hj < 4; hj++)
      #pragma unroll
      for (int mp = 0; mp < 8; mp++) {
        int v = hj*16 + 2*mp;
        int phys = (l << 6) + (v ^ swz);
        __hip_bfloat162 pk;
        pk.x = __float2bfloat16(acc[hj][2*mp]); pk.y = __float2bfloat16(acc[hj][2*mp+1]);
        *(__hip_bfloat162*)&s_new[p*1032 + phys] = pk;
      }
  }
  __syncthreads();

  // ---- phase 3: out = new(16x1024) @ lwb^T(1024x64) + linb via MFMA ----
  {
    const int wv = t >> 6, lane = t & 63, pt = lane & 15, kq = lane >> 4;
    const int j = wv * 16 + pt;
    const bf16* lwrow = lwb + j * 1024;
    f32x4 acc = {0.f, 0.f, 0.f, 0.f};
    #pragma unroll 8
    for (int ks = 0; ks < 32; ks++) {
      int i = ks*32 + kq*8;
      int l2 = i >> 6, v = i & 63;
      int phys = (l2 << 6) + (v ^ ((l2 & 7) * 8));
      bf16x8 av = *(const bf16x8*)&s_new[pt*1032 + phys];
      bf16x8 bv = *(const bf16x8*)(lwrow + i);
      acc = __builtin_amdgcn_mfma_f32_16x16x32_bf16(av, bv, acc, 0, 0, 0);
    }
    float bj = linb[j];
    float ss = 0.f, qq = 0.f;
    #pragma unroll
    for (int r = 0; r < 4; r++) {
      int gp = (int)(blockIdx.x * 16) + kq*4 + r;
      float val = acc[r] + bj;
      outp[(size_t)gp*64 + j] = val;
      ss += val; qq += val * val;
    }
    ss += __shfl_xor(ss, 16); ss += __shfl_xor(ss, 32);
    qq += __shfl_xor(qq, 16); qq += __shfl_xor(qq, 32);
    if (lane < 16) { s_ls[j] = ss; s_lq[j] = qq; }   // j unique per (wv,pt): plain store
  }
  __syncthreads();
  if (t < 128)
    part[Q_LIN + blockIdx.x * 128 + t] = (t < 64) ? s_ls[t] : s_lq[t - 64];
}

// ================= K6: final BN + ReLU in-place on d_out =================
__global__ __launch_bounds__(256) void k6(float* __restrict__ outp, const float* __restrict__ stats) {
  long e = (long)blockIdx.x * 256 + threadIdx.x;
  int j = (int)(e & 63);
  float sc = stats[F_LIN + j], sh = stats[F_LIN + 64 + j];
  float v = outp[e];
  outp[e] = fmaxf(fmaf(sc, v, sh), 0.f);
}

// signature if workspace too small: absmax ~= ws_size in MB
__global__ void k_wsfail(float* outp, float mb) {
  outp[threadIdx.x] = -mb;
}

extern "C" void kernel_launch(void* const* d_in, const int* in_sizes, int n_in,
                              void* d_out, int out_size, void* d_ws, size_t ws_size,
                              hipStream_t stream) {
  const float* xyz  = (const float*)d_in[0];
  const float* cov  = (const float*)d_in[1];
  const float* feats= (const float*)d_in[2];
  const int*   knn  = (const int*)d_in[3];
  const float* fw1  = (const float*)d_in[4];
  const float* fb1  = (const float*)d_in[5];
  const float* fg1  = (const float*)d_in[6];
  const float* fbe1 = (const float*)d_in[7];
  const float* fw2  = (const float*)d_in[8];
  const float* fb2  = (const float*)d_in[9];
  const float* fg2  = (const float*)d_in[10];
  const float* fbe2 = (const float*)d_in[11];
  const float* ww1  = (const float*)d_in[12];
  const float* wb1  = (const float*)d_in[13];
  const float* wg1  = (const float*)d_in[14];
  const float* wbe1 = (const float*)d_in[15];
  const float* ww2  = (const float*)d_in[16];
  const float* wb2  = (const float*)d_in[17];
  const float* wg2  = (const float*)d_in[18];
  const float* wbe2 = (const float*)d_in[19];
  const float* ww3  = (const float*)d_in[20];
  const float* wb3  = (const float*)d_in[21];
  const float* wg3  = (const float*)d_in[22];
  const float* wbe3 = (const float*)d_in[23];
  const float* linw = (const float*)d_in[24];
  const float* linb = (const float*)d_in[25];
  const float* bng  = (const float*)d_in[26];
  const float* bnb  = (const float*)d_in[27];

  float* outp = (float*)d_out;
  if (ws_size < WS_NEED) {
    hipLaunchKernelGGL(k_wsfail, dim3(1), dim3(256), 0, stream, outp, (float)(ws_size >> 20));
    return;
  }
  char* ws = (char*)d_ws;
  float* stats = (float*)ws;
  int*   cnt   = (int*)(ws + CNT_BYTE);
  bf16*  Y1    = (bf16*)(ws + OFS_Y1);
  float* zp1   = (float*)(ws + OFS_ZP1);
  bf16*  a2    = (bf16*)(ws + OFS_ZP1);   // overlays zp1 (dead after k3)
  float* zp2   = (float*)(ws + OFS_ZP2);
  float* P     = (float*)(ws + OFS_P);    // overlays zp2 (dead before k3 writes)
  float* part  = (float*)(ws + OFS_PART);
  bf16*  lwb   = (bf16*)(ws + OFS_LWB);

  hipMemsetAsync(d_ws, 0, ZERO_BYTES, stream);
  hipLaunchKernelGGL(k0, dim3(NB_P + 64), dim3(256), 0, stream,
                     xyz, cov, feats, linw, P, lwb);
  hipLaunchKernelGGL(k1, dim3(NB_W), dim3(256), 0, stream,
                     P, knn, ww1, wb1, part, cnt, Y1);
  hipLaunchKernelGGL(kredfin, dim3(16), dim3(256), 0, stream, part, stats,
                     Q_Y1, NB_W, 8, wg1, wbe1, (float)NKTOT, F_Y1,
                     Q_Y1, NB_W, 8, wg1, wbe1, (float)NKTOT, F_Y1);
  hipLaunchKernelGGL(k2, dim3(NB_W + NB_F), dim3(256), 0, stream,
                     Y1, ww2, wb2, feats, fw1, fb1, cnt, stats, part, zp1);
  hipLaunchKernelGGL(kredfin, dim3(72), dim3(256), 0, stream, part, stats,
                     Q_Y2, NB_W, 8, wg2, wbe2, (float)NKTOT, F_Y2,
                     Q_Z1, NB_F, 64, fg1, fbe1, (float)NKTOT, F_Z1);
  hipLaunchKernelGGL(k3, dim3(NB_W + NB_F), dim3(256), 0, stream,
                     Y1, ww2, wb2, ww3, wb3, zp1, fw2, fb2, cnt, stats, part, zp2);
  hipLaunchKernelGGL(kredfin, dim3(80), dim3(256), 0, stream, part, stats,
                     Q_Y3, NB_W, 16, wg3, wbe3, (float)NKTOT, F_Y3,
                     Q_Z2, NB_F, 64, fg2, fbe2, (float)NKTOT, F_Z2);
  hipLaunchKernelGGL(k3b, dim3(6250), dim3(256), 0, stream, zp2, stats, a2);
  hipLaunchKernelGGL(k4, dim3(NB_W), dim3(256), 0, stream,
                     Y1, knn, ww2, wb2, ww3, wb3, a2, lwb, linb, stats, part, outp);
  hipLaunchKernelGGL(kredfin, dim3(128), dim3(256), 0, stream, part, stats,
                     Q_LIN, NB_W, 64, bng, bnb, (float)NPTS, F_LIN,
                     Q_LIN, NB_W, 64, bng, bnb, (float)NPTS, F_LIN);
  hipLaunchKernelGGL(k6, dim3(25000), dim3(256), 0, stream, outp, stats);
}